// Round 12
// baseline (311.965 us; speedup 1.0000x reference)
//
#include <hip/hip_runtime.h>
#include <hip/hip_bf16.h>
#include <math.h>

#define NEG_SLOPE 0.2f

typedef __bf16 bf16x8 __attribute__((ext_vector_type(8)));
typedef float f32x4 __attribute__((ext_vector_type(4)));

__device__ __forceinline__ float lrelu(float x) { return x > 0.f ? x : NEG_SLOPE * x; }

__device__ __forceinline__ unsigned short f2bfu(float f) {
    unsigned int ua = __float_as_uint(f);
    return (unsigned short)((ua + 0x7fffu + ((ua >> 16) & 1u)) >> 16);
}
__device__ __forceinline__ float bfu2f(unsigned short u) {
    return __uint_as_float(((unsigned int)u) << 16);
}
__device__ __forceinline__ float bf_lo(unsigned int u) { return __uint_as_float(u << 16); }
__device__ __forceinline__ float bf_hi(unsigned int u) { return __uint_as_float(u & 0xffff0000u); }

// ---------------------------------------------------------------------------
// prep: zero cnt + repack W1 (2048 frags) + repack W2 (768 frags, pad 40->48)
// ---------------------------------------------------------------------------
__global__ __launch_bounds__(256) void k_prep(const float* __restrict__ W1,
                                              bf16x8* __restrict__ Wp,
                                              const float* __restrict__ W2,
                                              bf16x8* __restrict__ W2p,
                                              int* __restrict__ cnt, int N) {
    int g = blockIdx.x * 256 + threadIdx.x;
    if (g < 2048) {
        int n = g & 15, quad = (g >> 4) & 3, c = (g >> 6) & 3, ct = g >> 8;
        bf16x8 v;
#pragma unroll
        for (int j = 0; j < 8; ++j)
            v[j] = (__bf16)W1[(c * 32 + quad * 8 + j) * 128 + ct * 16 + n];
        Wp[g] = v;
    } else if (g < 2816) {
        int idx = g - 2048;
        int n = idx & 15, quad = (idx >> 4) & 3, c = (idx >> 6) & 3, ct = idx >> 8;
        int colc = ct * 16 + n;
        bf16x8 v;
#pragma unroll
        for (int j = 0; j < 8; ++j)
            v[j] = (colc < 40) ? (__bf16)W2[(c * 32 + quad * 8 + j) * 40 + colc] : (__bf16)0.f;
        W2p[idx] = v;
    }
    if (g < N) cnt[g] = 0;
}

// ---------------------------------------------------------------------------
// histogram of dst (incl. self-loops); emits rank[e] (ushort: max deg small)
// ---------------------------------------------------------------------------
__global__ __launch_bounds__(256) void k_hist(const int* __restrict__ ei, int E, int N,
                                              int* __restrict__ cnt,
                                              unsigned short* __restrict__ rank) {
    int e = blockIdx.x * 256 + threadIdx.x;
    if (e >= E + N) return;
    int d = (e < E) ? ei[E + e] : (e - E);
    rank[e] = (unsigned short)atomicAdd(&cnt[d], 1);
}

// ---------------------------------------------------------------------------
// single-block exclusive scan: 1024 threads, contiguous chunk per thread
// ---------------------------------------------------------------------------
__global__ __launch_bounds__(1024) void k_scan(const int* __restrict__ cnt, int N,
                                               int* __restrict__ rowptr) {
    __shared__ int sh[1024];
    int t = threadIdx.x;
    int chunk = (N + 1023) >> 10;
    int lo = t * chunk;
    int hi = lo + chunk; if (hi > N) hi = N;
    int s = 0;
    for (int i = lo; i < hi; ++i) s += cnt[i];
    sh[t] = s; __syncthreads();
    for (int off = 1; off < 1024; off <<= 1) {
        int v = (t >= off) ? sh[t - off] : 0;
        __syncthreads();
        sh[t] += v;
        __syncthreads();
    }
    int run = sh[t] - s;   // exclusive prefix of this thread's chunk
    for (int i = lo; i < hi; ++i) { rowptr[i] = run; run += cnt[i]; }
}

// ---------------------------------------------------------------------------
// scatter src into CSR by dst using precomputed rank (no atomics); col ushort
// ---------------------------------------------------------------------------
__global__ __launch_bounds__(256) void k_scatter(const int* __restrict__ ei, int E, int N,
                                                 const int* __restrict__ rowptr,
                                                 const unsigned short* __restrict__ rank,
                                                 unsigned short* __restrict__ col) {
    int e = blockIdx.x * 256 + threadIdx.x;
    if (e >= E + N) return;
    int s, d;
    if (e < E) { s = ei[e]; d = ei[E + e]; } else { s = d = e - E; }
    col[rowptr[d] + (int)rank[e]] = (unsigned short)s;
}

// ---------------------------------------------------------------------------
// GEMM1 via MFMA: h1 = x @ W1. One wave = 16 rows x 128 cols; x split hi/lo
// bf16; 64 mfma. No LDS. Emits channel-split packed-bf16 h1A/h1B (128 B rows
// = one cacheline) + fused fp32 a_src1/a_dst1.
// ---------------------------------------------------------------------------
__global__ __launch_bounds__(256) void k_gemm1(const float* __restrict__ x,
                                               const bf16x8* __restrict__ Wp,
                                               const float* __restrict__ att_s,
                                               const float* __restrict__ att_d,
                                               unsigned short* __restrict__ h1A,
                                               unsigned short* __restrict__ h1B,
                                               float* __restrict__ a_src,
                                               float* __restrict__ a_dst, int N) {
    int t = threadIdx.x;
    int w = t >> 6, lane = t & 63, quad = lane >> 4, n16 = lane & 15;
    int row0 = blockIdx.x * 64 + w * 16;
    int arow = row0 + n16; if (arow >= N) arow = N - 1;
    const float* px = x + (size_t)arow * 128;

    bf16x8 ah[4], al[4];
#pragma unroll
    for (int c = 0; c < 4; ++c) {
        float4 v0 = *(const float4*)&px[c * 32 + quad * 8];
        float4 v1 = *(const float4*)&px[c * 32 + quad * 8 + 4];
        float xf[8] = {v0.x, v0.y, v0.z, v0.w, v1.x, v1.y, v1.z, v1.w};
#pragma unroll
        for (int j = 0; j < 8; ++j) {
            __bf16 hi = (__bf16)xf[j];
            ah[c][j] = hi;
            al[c][j] = (__bf16)(xf[j] - (float)hi);
        }
    }

    f32x4 acc[8];
#pragma unroll
    for (int ct = 0; ct < 8; ++ct) acc[ct] = (f32x4){0.f, 0.f, 0.f, 0.f};

    const uint4* wp4 = (const uint4*)Wp;
#pragma unroll
    for (int ct = 0; ct < 8; ++ct) {
#pragma unroll
        for (int c = 0; c < 4; ++c) {
            union { uint4 u; bf16x8 b; } bu;
            bu.u = wp4[((ct * 4 + c) * 4 + quad) * 16 + n16];
            acc[ct] = __builtin_amdgcn_mfma_f32_16x16x32_bf16(ah[c], bu.b, acc[ct], 0, 0, 0);
            acc[ct] = __builtin_amdgcn_mfma_f32_16x16x32_bf16(al[c], bu.b, acc[ct], 0, 0, 0);
        }
    }

    float asv[8], adv[8];
#pragma unroll
    for (int ct = 0; ct < 8; ++ct) {
        asv[ct] = att_s[ct * 16 + n16];
        adv[ct] = att_d[ct * 16 + n16];
    }
    int nodeb = row0 + quad * 4;
#pragma unroll
    for (int ct = 0; ct < 8; ++ct) {
        unsigned short* hp = (ct < 4) ? h1A : h1B;
        int chl = (ct & 3) * 16 + n16;
#pragma unroll
        for (int reg = 0; reg < 4; ++reg) {
            int node = nodeb + reg;
            float hv = acc[ct][reg];
            float ps = hv * asv[ct];
            float pd = hv * adv[ct];
#pragma unroll
            for (int m = 1; m < 16; m <<= 1) {
                ps += __shfl_xor(ps, m);
                pd += __shfl_xor(pd, m);
            }
            if (node < N) {
                hp[(size_t)node * 64 + chl] = f2bfu(hv);
                if (n16 == 0) {
                    a_src[(size_t)node * 8 + ct] = ps;
                    a_dst[(size_t)node * 8 + ct] = pd;
                }
            }
        }
    }
}

// ---------------------------------------------------------------------------
// Layer-1 aggregation, channel-split pass p (p=0: ch 0-63 / heads 0-3;
// p=1: ch 64-127 / heads 4-7). 6.4 MB gather footprint, 128 B rows. Two
// nodes per wave (32 lanes); lane u owns channels p*64+2u,2u+1. Per 32-edge
// chunk lane u computes 4 evs for edge u (coalesced a_src float4 gather)
// into per-wave LDS strips (wave-synchronous). Emits out1 as hi/lo
// packed-bf16 pairs for MFMA GEMM2.
// ---------------------------------------------------------------------------
__global__ __launch_bounds__(256) void k_aggr1(const int* __restrict__ rowptr,
                                               const int* __restrict__ cnt,
                                               const unsigned short* __restrict__ col,
                                               const float* __restrict__ a_src,
                                               const float* __restrict__ a_dst,
                                               const unsigned int* __restrict__ hp,
                                               const float* __restrict__ bias1,
                                               unsigned int* __restrict__ out1h,
                                               unsigned int* __restrict__ out1l, int N, int p) {
    __shared__ float evs[4][2][128];   // [wave][half][edge*4+head]
    __shared__ int   cls[4][2][32];    // [wave][half][edge]
    int t = threadIdx.x;
    int w = t >> 6;
    int lane = t & 63;
    int half = lane >> 5;
    int u = lane & 31;
    int node = blockIdx.x * 8 + w * 2 + half;
    bool nv = (node < N);
    int nodec = nv ? node : (N - 1);
    int beg = rowptr[nodec];
    int deg = nv ? cnt[nodec] : 0;
    int degO = __shfl_xor(deg, 32);
    int degmax = (deg > degO) ? deg : degO;
    if (degmax <= 0) return;   // uniform across wave

    int hh = u >> 3;                           // phase-local head 0..3
    float4 ad4 = *(const float4*)&a_dst[(size_t)nodec * 8 + p * 4];

    float* myev = &evs[w][half][0];
    int*   mycl = &cls[w][half][0];

    float den = 0.f, n0 = 0.f, n1 = 0.f;
    int c = 0;
    while (c < degmax) {
        int slot = c + u;
        int slotc = (slot < deg) ? slot : (deg - 1);
        if (slotc < 0) slotc = 0;
        int su = (int)col[beg + slotc];
        float4 as4 = *(const float4*)&a_src[(size_t)su * 8 + p * 4];
        bool valid = (slot < deg);
        float e0 = valid ? __expf(lrelu(as4.x + ad4.x)) : 0.f;
        float e1 = valid ? __expf(lrelu(as4.y + ad4.y)) : 0.f;
        float e2 = valid ? __expf(lrelu(as4.z + ad4.z)) : 0.f;
        float e3 = valid ? __expf(lrelu(as4.w + ad4.w)) : 0.f;
        *(float4*)&myev[u * 4] = make_float4(e0, e1, e2, e3);
        mycl[u] = su;
        // wave-synchronous LDS: single-wave producer/consumer, no barrier

        int ccm = degmax - c; ccm = (ccm < 32) ? ccm : 32;
        int sP = mycl[0];
        unsigned int uP = hp[sP * 32 + u];
        for (int i = 0; i < ccm; ++i) {
            int in = (i + 1 < ccm) ? (i + 1) : i;
            int sN = mycl[in];
            unsigned int uN = hp[sN * 32 + u];
            float ev = myev[i * 4 + hh];
            den += ev;
            n0 = fmaf(ev, bf_lo(uP), n0);
            n1 = fmaf(ev, bf_hi(uP), n1);
            uP = uN;
        }
        c += 32;
    }
    if (nv) {
        float inv = 1.f / (den + 1e-16f);
        int ch = p * 64 + 2 * u;
        float2 b = *(const float2*)&bias1[ch];
        float o0 = fmaf(n0, inv, b.x), o1 = fmaf(n1, inv, b.y);
        unsigned short h0 = f2bfu(o0), h1 = f2bfu(o1);
        float l0 = o0 - bfu2f(h0), l1 = o1 - bfu2f(h1);
        size_t idx = (size_t)node * 64 + p * 32 + u;
        out1h[idx] = (unsigned int)h0 | ((unsigned int)h1 << 16);
        out1l[idx] = (unsigned int)f2bfu(l0) | ((unsigned int)f2bfu(l1) << 16);
    }
}

// ---------------------------------------------------------------------------
// GEMM2 via MFMA: h2 = out1 @ W2 ([N,128]@[128,40->48]); out1 consumed as
// hi/lo bf16; 24 mfma. Emits bf16 h2 rows + fused fp32 a_src2/a_dst2.
// ---------------------------------------------------------------------------
__global__ __launch_bounds__(256) void k_gemm2(const unsigned int* __restrict__ out1h,
                                               const unsigned int* __restrict__ out1l,
                                               const bf16x8* __restrict__ W2p,
                                               const float* __restrict__ att_s2,
                                               const float* __restrict__ att_d2,
                                               unsigned short* __restrict__ h2s,
                                               float* __restrict__ a_src2,
                                               float* __restrict__ a_dst2, int N) {
    int t = threadIdx.x;
    int w = t >> 6, lane = t & 63, quad = lane >> 4, n16 = lane & 15;
    int row0 = blockIdx.x * 64 + w * 16;
    int arow = row0 + n16; if (arow >= N) arow = N - 1;

    bf16x8 ah[4], al[4];
#pragma unroll
    for (int c = 0; c < 4; ++c) {
        size_t base = (size_t)arow * 64 + (c * 32 + quad * 8) / 2;
        union { uint4 u; bf16x8 b; } hu, lu;
        hu.u = *(const uint4*)&out1h[base];
        lu.u = *(const uint4*)&out1l[base];
        ah[c] = hu.b;
        al[c] = lu.b;
    }

    f32x4 acc[3];
#pragma unroll
    for (int ct = 0; ct < 3; ++ct) acc[ct] = (f32x4){0.f, 0.f, 0.f, 0.f};

    const uint4* wp4 = (const uint4*)W2p;
#pragma unroll
    for (int ct = 0; ct < 3; ++ct) {
#pragma unroll
        for (int c = 0; c < 4; ++c) {
            union { uint4 u; bf16x8 b; } bu;
            bu.u = wp4[((ct * 4 + c) * 4 + quad) * 16 + n16];
            acc[ct] = __builtin_amdgcn_mfma_f32_16x16x32_bf16(ah[c], bu.b, acc[ct], 0, 0, 0);
            acc[ct] = __builtin_amdgcn_mfma_f32_16x16x32_bf16(al[c], bu.b, acc[ct], 0, 0, 0);
        }
    }

    float asv[3], adv[3];
#pragma unroll
    for (int ct = 0; ct < 3; ++ct) {
        int ch = ct * 16 + n16;
        asv[ct] = (ch < 40) ? att_s2[ch] : 0.f;
        adv[ct] = (ch < 40) ? att_d2[ch] : 0.f;
    }
    int nodeb = row0 + quad * 4;
#pragma unroll
    for (int reg = 0; reg < 4; ++reg) {
        int node = nodeb + reg;
        float ps = 0.f, pd = 0.f;
#pragma unroll
        for (int ct = 0; ct < 3; ++ct) {
            float hv = acc[ct][reg];
            ps = fmaf(hv, asv[ct], ps);
            pd = fmaf(hv, adv[ct], pd);
            int ch = ct * 16 + n16;
            if (node < N && ch < 40) h2s[(size_t)node * 40 + ch] = f2bfu(hv);
        }
#pragma unroll
        for (int m = 1; m < 16; m <<= 1) {
            ps += __shfl_xor(ps, m);
            pd += __shfl_xor(pd, m);
        }
        if (node < N && n16 == 0) {
            a_src2[node] = ps;
            a_dst2[node] = pd;
        }
    }
}

// ---------------------------------------------------------------------------
// Layer-2 aggregation (H=1, C=40). Two nodes per wave (32 lanes each); lane
// u<20 owns channels 2u,2u+1 (4 MB h2 footprint). Writes final output
// (+bias2) directly.
// ---------------------------------------------------------------------------
__global__ __launch_bounds__(256) void k_aggr2(const int* __restrict__ rowptr,
                                               const int* __restrict__ cnt,
                                               const unsigned short* __restrict__ col,
                                               const float* __restrict__ a_src,
                                               const float* __restrict__ a_dst,
                                               const unsigned int* __restrict__ h2b,
                                               const float* __restrict__ bias2,
                                               float* __restrict__ out, int N) {
    __shared__ float evs[4][2][32];
    __shared__ int   cls[4][2][32];
    int t = threadIdx.x;
    int w = t >> 6;
    int lane = t & 63;
    int half = lane >> 5;
    int u = lane & 31;
    int node = blockIdx.x * 8 + w * 2 + half;
    bool nv = (node < N);
    int nodec = nv ? node : (N - 1);
    int beg = rowptr[nodec];
    int deg = nv ? cnt[nodec] : 0;
    int degO = __shfl_xor(deg, 32);
    int degmax = (deg > degO) ? deg : degO;
    if (degmax <= 0) return;

    int ucl = (u < 20) ? u : 19;
    float ad = a_dst[nodec];
    float* myev = &evs[w][half][0];
    int*   mycl = &cls[w][half][0];

    float den = 0.f, a0 = 0.f, a1 = 0.f;
    int c = 0;
    while (c < degmax) {
        int slot = c + u;
        int slotc = (slot < deg) ? slot : (deg - 1);
        if (slotc < 0) slotc = 0;
        int su = (int)col[beg + slotc];
        float ev = (slot < deg) ? __expf(lrelu(a_src[su] + ad)) : 0.f;
        myev[u] = ev;
        mycl[u] = su;

        int ccm = degmax - c; ccm = (ccm < 32) ? ccm : 32;
        int sP = mycl[0];
        unsigned int uP = h2b[sP * 20 + ucl];
        for (int i = 0; i < ccm; ++i) {
            int in = (i + 1 < ccm) ? (i + 1) : i;
            int sN = mycl[in];
            unsigned int uN = h2b[sN * 20 + ucl];
            float evv = myev[i];
            den += evv;
            a0 = fmaf(evv, bf_lo(uP), a0);
            a1 = fmaf(evv, bf_hi(uP), a1);
            uP = uN;
        }
        c += 32;
    }
    if (nv && u < 20) {
        float inv = 1.f / (den + 1e-16f);
        float2 b = *(const float2*)&bias2[2 * u];
        float2 o = make_float2(fmaf(a0, inv, b.x), fmaf(a1, inv, b.y));
        *(float2*)&out[(size_t)node * 40 + 2 * u] = o;
    }
}

// ---------------------------------------------------------------------------
extern "C" void kernel_launch(void* const* d_in, const int* in_sizes, int n_in,
                              void* d_out, int out_size, void* d_ws, size_t ws_size,
                              hipStream_t stream) {
    const float* x   = (const float*)d_in[0];
    const int*   ei  = (const int*)d_in[1];
    const float* W1  = (const float*)d_in[2];
    const float* as1 = (const float*)d_in[3];
    const float* ad1 = (const float*)d_in[4];
    const float* b1  = (const float*)d_in[5];
    const float* W2  = (const float*)d_in[6];
    const float* as2 = (const float*)d_in[7];
    const float* ad2 = (const float*)d_in[8];
    const float* b2  = (const float*)d_in[9];

    int N = in_sizes[0] / 128;
    int E = in_sizes[1] / 2;
    int EN = E + N;
    size_t Np = (size_t)((N + 3) & ~3);
    size_t ENp = ((size_t)EN + 3) & ~3;

    float* ws = (float*)d_ws;
    unsigned int* out1h = (unsigned int*)ws; ws += Np * 64;  // hi bf16 pairs
    unsigned int* out1l = (unsigned int*)ws; ws += Np * 64;  // lo bf16 pairs
    unsigned int* h1A = (unsigned int*)ws; ws += Np * 32;    // ch 0-63, bf16x2
    unsigned int* h1Bp = (unsigned int*)ws; ws += Np * 32;   // ch 64-127
    unsigned int* h2b = (unsigned int*)ws; ws += Np * 20;
    float* a_src1  = ws; ws += Np * 8;
    float* a_dst1  = ws; ws += Np * 8;
    float* a_src2v = ws; ws += Np;
    float* a_dst2v = ws; ws += Np;
    bf16x8* Wp  = (bf16x8*)ws; ws += 2048 * 4;               // 32 KB repacked W1
    bf16x8* W2p = (bf16x8*)ws; ws += 768 * 4;                // 12 KB repacked W2
    int* cnt    = (int*)ws; ws += Np;
    int* rowptr = (int*)ws; ws += Np;
    unsigned short* col  = (unsigned short*)ws; ws += ENp / 2 + 4;
    unsigned short* rank = (unsigned short*)ws; ws += ENp / 2 + 4;

    int npre = (N > 2816 ? N : 2816);
    k_prep<<<(npre + 255) / 256, 256, 0, stream>>>(W1, Wp, W2, W2p, cnt, N);
    k_hist<<<(EN + 255) / 256, 256, 0, stream>>>(ei, E, N, cnt, rank);
    k_scan<<<1, 1024, 0, stream>>>(cnt, N, rowptr);
    k_scatter<<<(EN + 255) / 256, 256, 0, stream>>>(ei, E, N, rowptr, rank, col);

    k_gemm1<<<(N + 63) / 64, 256, 0, stream>>>(x, Wp, as1, ad1,
                                               (unsigned short*)h1A, (unsigned short*)h1Bp,
                                               a_src1, a_dst1, N);
    int nag = (N + 7) / 8;
    k_aggr1<<<nag, 256, 0, stream>>>(rowptr, cnt, col, a_src1, a_dst1, h1A, b1, out1h, out1l, N, 0);
    k_aggr1<<<nag, 256, 0, stream>>>(rowptr, cnt, col, a_src1, a_dst1, h1Bp, b1, out1h, out1l, N, 1);
    k_gemm2<<<(N + 63) / 64, 256, 0, stream>>>(out1h, out1l, W2p, as2, ad2,
                                               (unsigned short*)h2b, a_src2v, a_dst2v, N);
    k_aggr2<<<nag, 256, 0, stream>>>(rowptr, cnt, col, a_src2v, a_dst2v, h2b, b2, (float*)d_out, N);
}

// Round 13
// 244.464 us; speedup vs baseline: 1.2761x; 1.2761x over previous
//
#include <hip/hip_runtime.h>
#include <hip/hip_bf16.h>
#include <math.h>

#define NEG_SLOPE 0.2f

typedef __bf16 bf16x8 __attribute__((ext_vector_type(8)));
typedef float f32x4 __attribute__((ext_vector_type(4)));

__device__ __forceinline__ float lrelu(float x) { return x > 0.f ? x : NEG_SLOPE * x; }

__device__ __forceinline__ unsigned short f2bfu(float f) {
    unsigned int ua = __float_as_uint(f);
    return (unsigned short)((ua + 0x7fffu + ((ua >> 16) & 1u)) >> 16);
}
__device__ __forceinline__ float bfu2f(unsigned short u) {
    return __uint_as_float(((unsigned int)u) << 16);
}
__device__ __forceinline__ float bf_lo(unsigned int u) { return __uint_as_float(u << 16); }
__device__ __forceinline__ float bf_hi(unsigned int u) { return __uint_as_float(u & 0xffff0000u); }

// ---------------------------------------------------------------------------
// prep: zero cnt + repack W1 (2048 frags) + repack W2 (768 frags, pad 40->48)
// ---------------------------------------------------------------------------
__global__ __launch_bounds__(256) void k_prep(const float* __restrict__ W1,
                                              bf16x8* __restrict__ Wp,
                                              const float* __restrict__ W2,
                                              bf16x8* __restrict__ W2p,
                                              int* __restrict__ cnt, int N) {
    int g = blockIdx.x * 256 + threadIdx.x;
    if (g < 2048) {
        int n = g & 15, quad = (g >> 4) & 3, c = (g >> 6) & 3, ct = g >> 8;
        bf16x8 v;
#pragma unroll
        for (int j = 0; j < 8; ++j)
            v[j] = (__bf16)W1[(c * 32 + quad * 8 + j) * 128 + ct * 16 + n];
        Wp[g] = v;
    } else if (g < 2816) {
        int idx = g - 2048;
        int n = idx & 15, quad = (idx >> 4) & 3, c = (idx >> 6) & 3, ct = idx >> 8;
        int colc = ct * 16 + n;
        bf16x8 v;
#pragma unroll
        for (int j = 0; j < 8; ++j)
            v[j] = (colc < 40) ? (__bf16)W2[(c * 32 + quad * 8 + j) * 40 + colc] : (__bf16)0.f;
        W2p[idx] = v;
    }
    if (g < N) cnt[g] = 0;
}

// ---------------------------------------------------------------------------
// histogram of dst (incl. self-loops); emits rank[e] (ushort: max deg small)
// ---------------------------------------------------------------------------
__global__ __launch_bounds__(256) void k_hist(const int* __restrict__ ei, int E, int N,
                                              int* __restrict__ cnt,
                                              unsigned short* __restrict__ rank) {
    int e = blockIdx.x * 256 + threadIdx.x;
    if (e >= E + N) return;
    int d = (e < E) ? ei[E + e] : (e - E);
    rank[e] = (unsigned short)atomicAdd(&cnt[d], 1);
}

// ---------------------------------------------------------------------------
// 3-stage exclusive scan of cnt[N] -> rowptr[N]; chunk = 1024 per block
// ---------------------------------------------------------------------------
__global__ __launch_bounds__(256) void k_scan_part(const int* __restrict__ cnt, int N,
                                                   int* __restrict__ psum) {
    __shared__ int sh[256];
    int t = threadIdx.x;
    int base = blockIdx.x * 1024 + t * 4;
    int tl = 0;
#pragma unroll
    for (int j = 0; j < 4; ++j) tl += (base + j < N) ? cnt[base + j] : 0;
    sh[t] = tl; __syncthreads();
    for (int off = 128; off > 0; off >>= 1) {
        if (t < off) sh[t] += sh[t + off];
        __syncthreads();
    }
    if (t == 0) psum[blockIdx.x] = sh[0];
}

__global__ __launch_bounds__(256) void k_scan_mid(int* __restrict__ psum, int nb) {
    __shared__ int sh[256];
    int t = threadIdx.x;
    int v = (t < nb) ? psum[t] : 0;
    sh[t] = v; __syncthreads();
    for (int off = 1; off < 256; off <<= 1) {
        int a = (t >= off) ? sh[t - off] : 0;
        __syncthreads();
        sh[t] += a;
        __syncthreads();
    }
    psum[t] = sh[t] - v;  // exclusive
}

__global__ __launch_bounds__(256) void k_scan_add(const int* __restrict__ cnt, int N,
                                                  const int* __restrict__ psum,
                                                  int* __restrict__ rowptr) {
    __shared__ int sh[256];
    int t = threadIdx.x;
    int base = blockIdx.x * 1024 + t * 4;
    int c[4]; int tl = 0;
#pragma unroll
    for (int j = 0; j < 4; ++j) { c[j] = (base + j < N) ? cnt[base + j] : 0; tl += c[j]; }
    sh[t] = tl; __syncthreads();
    for (int off = 1; off < 256; off <<= 1) {
        int a = (t >= off) ? sh[t - off] : 0;
        __syncthreads();
        sh[t] += a;
        __syncthreads();
    }
    int run = psum[blockIdx.x] + (sh[t] - tl);
#pragma unroll
    for (int j = 0; j < 4; ++j) {
        if (base + j < N) { rowptr[base + j] = run; run += c[j]; }
    }
}

// ---------------------------------------------------------------------------
// scatter src into CSR by dst using precomputed rank (no atomics); col ushort
// ---------------------------------------------------------------------------
__global__ __launch_bounds__(256) void k_scatter(const int* __restrict__ ei, int E, int N,
                                                 const int* __restrict__ rowptr,
                                                 const unsigned short* __restrict__ rank,
                                                 unsigned short* __restrict__ col) {
    int e = blockIdx.x * 256 + threadIdx.x;
    if (e >= E + N) return;
    int s, d;
    if (e < E) { s = ei[e]; d = ei[E + e]; } else { s = d = e - E; }
    col[rowptr[d] + (int)rank[e]] = (unsigned short)s;
}

// ---------------------------------------------------------------------------
// GEMM1 via MFMA: h1 = x @ W1. One wave = 16 rows x 128 cols; x split hi/lo
// bf16; 64 mfma. No LDS. Emits channel-split packed-bf16 h1A/h1B (128 B rows
// = one cacheline) + fused fp32 a_src1/a_dst1.
// ---------------------------------------------------------------------------
__global__ __launch_bounds__(256) void k_gemm1(const float* __restrict__ x,
                                               const bf16x8* __restrict__ Wp,
                                               const float* __restrict__ att_s,
                                               const float* __restrict__ att_d,
                                               unsigned short* __restrict__ h1A,
                                               unsigned short* __restrict__ h1B,
                                               float* __restrict__ a_src,
                                               float* __restrict__ a_dst, int N) {
    int t = threadIdx.x;
    int w = t >> 6, lane = t & 63, quad = lane >> 4, n16 = lane & 15;
    int row0 = blockIdx.x * 64 + w * 16;
    int arow = row0 + n16; if (arow >= N) arow = N - 1;
    const float* px = x + (size_t)arow * 128;

    bf16x8 ah[4], al[4];
#pragma unroll
    for (int c = 0; c < 4; ++c) {
        float4 v0 = *(const float4*)&px[c * 32 + quad * 8];
        float4 v1 = *(const float4*)&px[c * 32 + quad * 8 + 4];
        float xf[8] = {v0.x, v0.y, v0.z, v0.w, v1.x, v1.y, v1.z, v1.w};
#pragma unroll
        for (int j = 0; j < 8; ++j) {
            __bf16 hi = (__bf16)xf[j];
            ah[c][j] = hi;
            al[c][j] = (__bf16)(xf[j] - (float)hi);
        }
    }

    f32x4 acc[8];
#pragma unroll
    for (int ct = 0; ct < 8; ++ct) acc[ct] = (f32x4){0.f, 0.f, 0.f, 0.f};

    const uint4* wp4 = (const uint4*)Wp;
#pragma unroll
    for (int ct = 0; ct < 8; ++ct) {
#pragma unroll
        for (int c = 0; c < 4; ++c) {
            union { uint4 u; bf16x8 b; } bu;
            bu.u = wp4[((ct * 4 + c) * 4 + quad) * 16 + n16];
            acc[ct] = __builtin_amdgcn_mfma_f32_16x16x32_bf16(ah[c], bu.b, acc[ct], 0, 0, 0);
            acc[ct] = __builtin_amdgcn_mfma_f32_16x16x32_bf16(al[c], bu.b, acc[ct], 0, 0, 0);
        }
    }

    float asv[8], adv[8];
#pragma unroll
    for (int ct = 0; ct < 8; ++ct) {
        asv[ct] = att_s[ct * 16 + n16];
        adv[ct] = att_d[ct * 16 + n16];
    }
    int nodeb = row0 + quad * 4;
#pragma unroll
    for (int ct = 0; ct < 8; ++ct) {
        unsigned short* hp = (ct < 4) ? h1A : h1B;
        int chl = (ct & 3) * 16 + n16;
#pragma unroll
        for (int reg = 0; reg < 4; ++reg) {
            int node = nodeb + reg;
            float hv = acc[ct][reg];
            float ps = hv * asv[ct];
            float pd = hv * adv[ct];
#pragma unroll
            for (int m = 1; m < 16; m <<= 1) {
                ps += __shfl_xor(ps, m);
                pd += __shfl_xor(pd, m);
            }
            if (node < N) {
                hp[(size_t)node * 64 + chl] = f2bfu(hv);
                if (n16 == 0) {
                    a_src[(size_t)node * 8 + ct] = ps;
                    a_dst[(size_t)node * 8 + ct] = pd;
                }
            }
        }
    }
}

// ---------------------------------------------------------------------------
// Layer-1 aggregation, channel-split pass p (p=0: ch 0-63 / heads 0-3;
// p=1: ch 64-127 / heads 4-7). 6.4 MB gather footprint, 128 B rows. Two
// nodes per wave (32 lanes); lane u owns channels p*64+2u,2u+1. Per 32-edge
// chunk lane u computes 4 evs for edge u (coalesced a_src float4 gather)
// into per-wave LDS strips (wave-synchronous). Emits out1 as hi/lo
// packed-bf16 pairs for MFMA GEMM2.
// ---------------------------------------------------------------------------
__global__ __launch_bounds__(256) void k_aggr1(const int* __restrict__ rowptr,
                                               const int* __restrict__ cnt,
                                               const unsigned short* __restrict__ col,
                                               const float* __restrict__ a_src,
                                               const float* __restrict__ a_dst,
                                               const unsigned int* __restrict__ hp,
                                               const float* __restrict__ bias1,
                                               unsigned int* __restrict__ out1h,
                                               unsigned int* __restrict__ out1l, int N, int p) {
    __shared__ float evs[4][2][128];   // [wave][half][edge*4+head]
    __shared__ int   cls[4][2][32];    // [wave][half][edge]
    int t = threadIdx.x;
    int w = t >> 6;
    int lane = t & 63;
    int half = lane >> 5;
    int u = lane & 31;
    int node = blockIdx.x * 8 + w * 2 + half;
    bool nv = (node < N);
    int nodec = nv ? node : (N - 1);
    int beg = rowptr[nodec];
    int deg = nv ? cnt[nodec] : 0;
    int degO = __shfl_xor(deg, 32);
    int degmax = (deg > degO) ? deg : degO;
    if (degmax <= 0) return;   // uniform across wave

    int hh = u >> 3;                           // phase-local head 0..3
    float4 ad4 = *(const float4*)&a_dst[(size_t)nodec * 8 + p * 4];

    float* myev = &evs[w][half][0];
    int*   mycl = &cls[w][half][0];

    float den = 0.f, n0 = 0.f, n1 = 0.f;
    int c = 0;
    while (c < degmax) {
        int slot = c + u;
        int slotc = (slot < deg) ? slot : (deg - 1);
        if (slotc < 0) slotc = 0;
        int su = (int)col[beg + slotc];
        float4 as4 = *(const float4*)&a_src[(size_t)su * 8 + p * 4];
        bool valid = (slot < deg);
        float e0 = valid ? __expf(lrelu(as4.x + ad4.x)) : 0.f;
        float e1 = valid ? __expf(lrelu(as4.y + ad4.y)) : 0.f;
        float e2 = valid ? __expf(lrelu(as4.z + ad4.z)) : 0.f;
        float e3 = valid ? __expf(lrelu(as4.w + ad4.w)) : 0.f;
        *(float4*)&myev[u * 4] = make_float4(e0, e1, e2, e3);
        mycl[u] = su;
        // wave-synchronous LDS: single-wave producer/consumer, no barrier

        int ccm = degmax - c; ccm = (ccm < 32) ? ccm : 32;
        int sP = mycl[0];
        unsigned int uP = hp[sP * 32 + u];
        for (int i = 0; i < ccm; ++i) {
            int in = (i + 1 < ccm) ? (i + 1) : i;
            int sN = mycl[in];
            unsigned int uN = hp[sN * 32 + u];
            float ev = myev[i * 4 + hh];
            den += ev;
            n0 = fmaf(ev, bf_lo(uP), n0);
            n1 = fmaf(ev, bf_hi(uP), n1);
            uP = uN;
        }
        c += 32;
    }
    if (nv) {
        float inv = 1.f / (den + 1e-16f);
        int ch = p * 64 + 2 * u;
        float2 b = *(const float2*)&bias1[ch];
        float o0 = fmaf(n0, inv, b.x), o1 = fmaf(n1, inv, b.y);
        unsigned short h0 = f2bfu(o0), h1 = f2bfu(o1);
        float l0 = o0 - bfu2f(h0), l1 = o1 - bfu2f(h1);
        size_t idx = (size_t)node * 64 + p * 32 + u;
        out1h[idx] = (unsigned int)h0 | ((unsigned int)h1 << 16);
        out1l[idx] = (unsigned int)f2bfu(l0) | ((unsigned int)f2bfu(l1) << 16);
    }
}

// ---------------------------------------------------------------------------
// GEMM2 via MFMA: h2 = out1 @ W2 ([N,128]@[128,40->48]); out1 consumed as
// hi/lo bf16; 24 mfma. Emits bf16 h2 rows + fused fp32 a_src2/a_dst2.
// ---------------------------------------------------------------------------
__global__ __launch_bounds__(256) void k_gemm2(const unsigned int* __restrict__ out1h,
                                               const unsigned int* __restrict__ out1l,
                                               const bf16x8* __restrict__ W2p,
                                               const float* __restrict__ att_s2,
                                               const float* __restrict__ att_d2,
                                               unsigned short* __restrict__ h2s,
                                               float* __restrict__ a_src2,
                                               float* __restrict__ a_dst2, int N) {
    int t = threadIdx.x;
    int w = t >> 6, lane = t & 63, quad = lane >> 4, n16 = lane & 15;
    int row0 = blockIdx.x * 64 + w * 16;
    int arow = row0 + n16; if (arow >= N) arow = N - 1;

    bf16x8 ah[4], al[4];
#pragma unroll
    for (int c = 0; c < 4; ++c) {
        size_t base = (size_t)arow * 64 + (c * 32 + quad * 8) / 2;
        union { uint4 u; bf16x8 b; } hu, lu;
        hu.u = *(const uint4*)&out1h[base];
        lu.u = *(const uint4*)&out1l[base];
        ah[c] = hu.b;
        al[c] = lu.b;
    }

    f32x4 acc[3];
#pragma unroll
    for (int ct = 0; ct < 3; ++ct) acc[ct] = (f32x4){0.f, 0.f, 0.f, 0.f};

    const uint4* wp4 = (const uint4*)W2p;
#pragma unroll
    for (int ct = 0; ct < 3; ++ct) {
#pragma unroll
        for (int c = 0; c < 4; ++c) {
            union { uint4 u; bf16x8 b; } bu;
            bu.u = wp4[((ct * 4 + c) * 4 + quad) * 16 + n16];
            acc[ct] = __builtin_amdgcn_mfma_f32_16x16x32_bf16(ah[c], bu.b, acc[ct], 0, 0, 0);
            acc[ct] = __builtin_amdgcn_mfma_f32_16x16x32_bf16(al[c], bu.b, acc[ct], 0, 0, 0);
        }
    }

    float asv[3], adv[3];
#pragma unroll
    for (int ct = 0; ct < 3; ++ct) {
        int ch = ct * 16 + n16;
        asv[ct] = (ch < 40) ? att_s2[ch] : 0.f;
        adv[ct] = (ch < 40) ? att_d2[ch] : 0.f;
    }
    int nodeb = row0 + quad * 4;
#pragma unroll
    for (int reg = 0; reg < 4; ++reg) {
        int node = nodeb + reg;
        float ps = 0.f, pd = 0.f;
#pragma unroll
        for (int ct = 0; ct < 3; ++ct) {
            float hv = acc[ct][reg];
            ps = fmaf(hv, asv[ct], ps);
            pd = fmaf(hv, adv[ct], pd);
            int ch = ct * 16 + n16;
            if (node < N && ch < 40) h2s[(size_t)node * 40 + ch] = f2bfu(hv);
        }
#pragma unroll
        for (int m = 1; m < 16; m <<= 1) {
            ps += __shfl_xor(ps, m);
            pd += __shfl_xor(pd, m);
        }
        if (node < N && n16 == 0) {
            a_src2[node] = ps;
            a_dst2[node] = pd;
        }
    }
}

// ---------------------------------------------------------------------------
// Layer-2 aggregation (H=1, C=40). Two nodes per wave (32 lanes each); lane
// u<20 owns channels 2u,2u+1 (4 MB h2 footprint). Writes final output
// (+bias2) directly.
// ---------------------------------------------------------------------------
__global__ __launch_bounds__(256) void k_aggr2(const int* __restrict__ rowptr,
                                               const int* __restrict__ cnt,
                                               const unsigned short* __restrict__ col,
                                               const float* __restrict__ a_src,
                                               const float* __restrict__ a_dst,
                                               const unsigned int* __restrict__ h2b,
                                               const float* __restrict__ bias2,
                                               float* __restrict__ out, int N) {
    __shared__ float evs[4][2][32];
    __shared__ int   cls[4][2][32];
    int t = threadIdx.x;
    int w = t >> 6;
    int lane = t & 63;
    int half = lane >> 5;
    int u = lane & 31;
    int node = blockIdx.x * 8 + w * 2 + half;
    bool nv = (node < N);
    int nodec = nv ? node : (N - 1);
    int beg = rowptr[nodec];
    int deg = nv ? cnt[nodec] : 0;
    int degO = __shfl_xor(deg, 32);
    int degmax = (deg > degO) ? deg : degO;
    if (degmax <= 0) return;

    int ucl = (u < 20) ? u : 19;
    float ad = a_dst[nodec];
    float* myev = &evs[w][half][0];
    int*   mycl = &cls[w][half][0];

    float den = 0.f, a0 = 0.f, a1 = 0.f;
    int c = 0;
    while (c < degmax) {
        int slot = c + u;
        int slotc = (slot < deg) ? slot : (deg - 1);
        if (slotc < 0) slotc = 0;
        int su = (int)col[beg + slotc];
        float ev = (slot < deg) ? __expf(lrelu(a_src[su] + ad)) : 0.f;
        myev[u] = ev;
        mycl[u] = su;

        int ccm = degmax - c; ccm = (ccm < 32) ? ccm : 32;
        int sP = mycl[0];
        unsigned int uP = h2b[sP * 20 + ucl];
        for (int i = 0; i < ccm; ++i) {
            int in = (i + 1 < ccm) ? (i + 1) : i;
            int sN = mycl[in];
            unsigned int uN = h2b[sN * 20 + ucl];
            float evv = myev[i];
            den += evv;
            a0 = fmaf(evv, bf_lo(uP), a0);
            a1 = fmaf(evv, bf_hi(uP), a1);
            uP = uN;
        }
        c += 32;
    }
    if (nv && u < 20) {
        float inv = 1.f / (den + 1e-16f);
        float2 b = *(const float2*)&bias2[2 * u];
        float2 o = make_float2(fmaf(a0, inv, b.x), fmaf(a1, inv, b.y));
        *(float2*)&out[(size_t)node * 40 + 2 * u] = o;
    }
}

// ---------------------------------------------------------------------------
extern "C" void kernel_launch(void* const* d_in, const int* in_sizes, int n_in,
                              void* d_out, int out_size, void* d_ws, size_t ws_size,
                              hipStream_t stream) {
    const float* x   = (const float*)d_in[0];
    const int*   ei  = (const int*)d_in[1];
    const float* W1  = (const float*)d_in[2];
    const float* as1 = (const float*)d_in[3];
    const float* ad1 = (const float*)d_in[4];
    const float* b1  = (const float*)d_in[5];
    const float* W2  = (const float*)d_in[6];
    const float* as2 = (const float*)d_in[7];
    const float* ad2 = (const float*)d_in[8];
    const float* b2  = (const float*)d_in[9];

    int N = in_sizes[0] / 128;
    int E = in_sizes[1] / 2;
    int EN = E + N;
    size_t Np = (size_t)((N + 3) & ~3);
    size_t ENp = ((size_t)EN + 3) & ~3;

    float* ws = (float*)d_ws;
    unsigned int* out1h = (unsigned int*)ws; ws += Np * 64;  // hi bf16 pairs
    unsigned int* out1l = (unsigned int*)ws; ws += Np * 64;  // lo bf16 pairs
    unsigned int* h1A = (unsigned int*)ws; ws += Np * 32;    // ch 0-63, bf16x2
    unsigned int* h1Bp = (unsigned int*)ws; ws += Np * 32;   // ch 64-127
    unsigned int* h2b = (unsigned int*)ws; ws += Np * 20;
    float* a_src1  = ws; ws += Np * 8;
    float* a_dst1  = ws; ws += Np * 8;
    float* a_src2v = ws; ws += Np;
    float* a_dst2v = ws; ws += Np;
    bf16x8* Wp  = (bf16x8*)ws; ws += 2048 * 4;               // 32 KB repacked W1
    bf16x8* W2p = (bf16x8*)ws; ws += 768 * 4;                // 12 KB repacked W2
    int* cnt    = (int*)ws; ws += Np;
    int* rowptr = (int*)ws; ws += Np;
    int* psum   = (int*)ws; ws += 256;
    unsigned short* col  = (unsigned short*)ws; ws += ENp / 2 + 4;
    unsigned short* rank = (unsigned short*)ws; ws += ENp / 2 + 4;

    int nb = (N + 1023) / 1024;  // scan blocks (<=256)
    int npre = (N > 2816 ? N : 2816);

    k_prep<<<(npre + 255) / 256, 256, 0, stream>>>(W1, Wp, W2, W2p, cnt, N);
    k_hist<<<(EN + 255) / 256, 256, 0, stream>>>(ei, E, N, cnt, rank);
    k_scan_part<<<nb, 256, 0, stream>>>(cnt, N, psum);
    k_scan_mid<<<1, 256, 0, stream>>>(psum, nb);
    k_scan_add<<<nb, 256, 0, stream>>>(cnt, N, psum, rowptr);
    k_scatter<<<(EN + 255) / 256, 256, 0, stream>>>(ei, E, N, rowptr, rank, col);

    k_gemm1<<<(N + 63) / 64, 256, 0, stream>>>(x, Wp, as1, ad1,
                                               (unsigned short*)h1A, (unsigned short*)h1Bp,
                                               a_src1, a_dst1, N);
    int nag = (N + 7) / 8;
    k_aggr1<<<nag, 256, 0, stream>>>(rowptr, cnt, col, a_src1, a_dst1, h1A, b1, out1h, out1l, N, 0);
    k_aggr1<<<nag, 256, 0, stream>>>(rowptr, cnt, col, a_src1, a_dst1, h1Bp, b1, out1h, out1l, N, 1);
    k_gemm2<<<(N + 63) / 64, 256, 0, stream>>>(out1h, out1l, W2p, as2, ad2,
                                               (unsigned short*)h2b, a_src2v, a_dst2v, N);
    k_aggr2<<<nag, 256, 0, stream>>>(rowptr, cnt, col, a_src2v, a_dst2v, h2b, b2, (float*)d_out, N);
}

// Round 14
// 242.945 us; speedup vs baseline: 1.2841x; 1.0063x over previous
//
#include <hip/hip_runtime.h>
#include <hip/hip_bf16.h>
#include <math.h>

#define NEG_SLOPE 0.2f

typedef __bf16 bf16x8 __attribute__((ext_vector_type(8)));
typedef float f32x4 __attribute__((ext_vector_type(4)));

__device__ __forceinline__ float lrelu(float x) { return x > 0.f ? x : NEG_SLOPE * x; }

__device__ __forceinline__ unsigned short f2bfu(float f) {
    unsigned int ua = __float_as_uint(f);
    return (unsigned short)((ua + 0x7fffu + ((ua >> 16) & 1u)) >> 16);
}
__device__ __forceinline__ float bfu2f(unsigned short u) {
    return __uint_as_float(((unsigned int)u) << 16);
}
__device__ __forceinline__ float bf_lo(unsigned int u) { return __uint_as_float(u << 16); }
__device__ __forceinline__ float bf_hi(unsigned int u) { return __uint_as_float(u & 0xffff0000u); }

// ---------------------------------------------------------------------------
// prep: zero cnt + repack W1 (2048 frags) + repack W2 (768 frags, pad 40->48)
// ---------------------------------------------------------------------------
__global__ __launch_bounds__(256) void k_prep(const float* __restrict__ W1,
                                              bf16x8* __restrict__ Wp,
                                              const float* __restrict__ W2,
                                              bf16x8* __restrict__ W2p,
                                              int* __restrict__ cnt, int N) {
    int g = blockIdx.x * 256 + threadIdx.x;
    if (g < 2048) {
        int n = g & 15, quad = (g >> 4) & 3, c = (g >> 6) & 3, ct = g >> 8;
        bf16x8 v;
#pragma unroll
        for (int j = 0; j < 8; ++j)
            v[j] = (__bf16)W1[(c * 32 + quad * 8 + j) * 128 + ct * 16 + n];
        Wp[g] = v;
    } else if (g < 2816) {
        int idx = g - 2048;
        int n = idx & 15, quad = (idx >> 4) & 3, c = (idx >> 6) & 3, ct = idx >> 8;
        int colc = ct * 16 + n;
        bf16x8 v;
#pragma unroll
        for (int j = 0; j < 8; ++j)
            v[j] = (colc < 40) ? (__bf16)W2[(c * 32 + quad * 8 + j) * 40 + colc] : (__bf16)0.f;
        W2p[idx] = v;
    }
    if (g < N) cnt[g] = 0;
}

// ---------------------------------------------------------------------------
// histogram of dst (incl. self-loops); emits rank[e] (ushort: max deg small)
// ---------------------------------------------------------------------------
__global__ __launch_bounds__(256) void k_hist(const int* __restrict__ ei, int E, int N,
                                              int* __restrict__ cnt,
                                              unsigned short* __restrict__ rank) {
    int e = blockIdx.x * 256 + threadIdx.x;
    if (e >= E + N) return;
    int d = (e < E) ? ei[E + e] : (e - E);
    rank[e] = (unsigned short)atomicAdd(&cnt[d], 1);
}

// ---------------------------------------------------------------------------
// 2-stage exclusive scan of cnt[N] -> rowptr[N]; chunk = 1024 per block.
// Stage B inlines the per-block psum prefix (nb <= 256, L2-hot scalar loop).
// ---------------------------------------------------------------------------
__global__ __launch_bounds__(256) void k_scan_part(const int* __restrict__ cnt, int N,
                                                   int* __restrict__ psum) {
    __shared__ int sh[256];
    int t = threadIdx.x;
    int base = blockIdx.x * 1024 + t * 4;
    int tl = 0;
#pragma unroll
    for (int j = 0; j < 4; ++j) tl += (base + j < N) ? cnt[base + j] : 0;
    sh[t] = tl; __syncthreads();
    for (int off = 128; off > 0; off >>= 1) {
        if (t < off) sh[t] += sh[t + off];
        __syncthreads();
    }
    if (t == 0) psum[blockIdx.x] = sh[0];
}

__global__ __launch_bounds__(256) void k_scan_add(const int* __restrict__ cnt, int N,
                                                  const int* __restrict__ psum,
                                                  int* __restrict__ rowptr) {
    __shared__ int sh[256];
    __shared__ int basep;
    int t = threadIdx.x;
    if (t == 0) {
        int s = 0;
        for (int i = 0; i < blockIdx.x; ++i) s += psum[i];
        basep = s;
    }
    int base = blockIdx.x * 1024 + t * 4;
    int c[4]; int tl = 0;
#pragma unroll
    for (int j = 0; j < 4; ++j) { c[j] = (base + j < N) ? cnt[base + j] : 0; tl += c[j]; }
    sh[t] = tl; __syncthreads();
    for (int off = 1; off < 256; off <<= 1) {
        int a = (t >= off) ? sh[t - off] : 0;
        __syncthreads();
        sh[t] += a;
        __syncthreads();
    }
    int run = basep + (sh[t] - tl);
#pragma unroll
    for (int j = 0; j < 4; ++j) {
        if (base + j < N) { rowptr[base + j] = run; run += c[j]; }
    }
}

// ---------------------------------------------------------------------------
// scatter src into CSR by dst using precomputed rank (no atomics); col ushort
// ---------------------------------------------------------------------------
__global__ __launch_bounds__(256) void k_scatter(const int* __restrict__ ei, int E, int N,
                                                 const int* __restrict__ rowptr,
                                                 const unsigned short* __restrict__ rank,
                                                 unsigned short* __restrict__ col) {
    int e = blockIdx.x * 256 + threadIdx.x;
    if (e >= E + N) return;
    int s, d;
    if (e < E) { s = ei[e]; d = ei[E + e]; } else { s = d = e - E; }
    col[rowptr[d] + (int)rank[e]] = (unsigned short)s;
}

// ---------------------------------------------------------------------------
// GEMM1 via MFMA: h1 = x @ W1. One wave = 16 rows x 128 cols; x split hi/lo
// bf16; 64 mfma. No LDS. Emits channel-split packed-bf16 h1A/h1B (128 B rows
// = one cacheline) + fused fp32 a_src1/a_dst1.
// ---------------------------------------------------------------------------
__global__ __launch_bounds__(256) void k_gemm1(const float* __restrict__ x,
                                               const bf16x8* __restrict__ Wp,
                                               const float* __restrict__ att_s,
                                               const float* __restrict__ att_d,
                                               unsigned short* __restrict__ h1A,
                                               unsigned short* __restrict__ h1B,
                                               float* __restrict__ a_src,
                                               float* __restrict__ a_dst, int N) {
    int t = threadIdx.x;
    int w = t >> 6, lane = t & 63, quad = lane >> 4, n16 = lane & 15;
    int row0 = blockIdx.x * 64 + w * 16;
    int arow = row0 + n16; if (arow >= N) arow = N - 1;
    const float* px = x + (size_t)arow * 128;

    bf16x8 ah[4], al[4];
#pragma unroll
    for (int c = 0; c < 4; ++c) {
        float4 v0 = *(const float4*)&px[c * 32 + quad * 8];
        float4 v1 = *(const float4*)&px[c * 32 + quad * 8 + 4];
        float xf[8] = {v0.x, v0.y, v0.z, v0.w, v1.x, v1.y, v1.z, v1.w};
#pragma unroll
        for (int j = 0; j < 8; ++j) {
            __bf16 hi = (__bf16)xf[j];
            ah[c][j] = hi;
            al[c][j] = (__bf16)(xf[j] - (float)hi);
        }
    }

    f32x4 acc[8];
#pragma unroll
    for (int ct = 0; ct < 8; ++ct) acc[ct] = (f32x4){0.f, 0.f, 0.f, 0.f};

    const uint4* wp4 = (const uint4*)Wp;
#pragma unroll
    for (int ct = 0; ct < 8; ++ct) {
#pragma unroll
        for (int c = 0; c < 4; ++c) {
            union { uint4 u; bf16x8 b; } bu;
            bu.u = wp4[((ct * 4 + c) * 4 + quad) * 16 + n16];
            acc[ct] = __builtin_amdgcn_mfma_f32_16x16x32_bf16(ah[c], bu.b, acc[ct], 0, 0, 0);
            acc[ct] = __builtin_amdgcn_mfma_f32_16x16x32_bf16(al[c], bu.b, acc[ct], 0, 0, 0);
        }
    }

    float asv[8], adv[8];
#pragma unroll
    for (int ct = 0; ct < 8; ++ct) {
        asv[ct] = att_s[ct * 16 + n16];
        adv[ct] = att_d[ct * 16 + n16];
    }
    int nodeb = row0 + quad * 4;
#pragma unroll
    for (int ct = 0; ct < 8; ++ct) {
        unsigned short* hp = (ct < 4) ? h1A : h1B;
        int chl = (ct & 3) * 16 + n16;
#pragma unroll
        for (int reg = 0; reg < 4; ++reg) {
            int node = nodeb + reg;
            float hv = acc[ct][reg];
            float ps = hv * asv[ct];
            float pd = hv * adv[ct];
#pragma unroll
            for (int m = 1; m < 16; m <<= 1) {
                ps += __shfl_xor(ps, m);
                pd += __shfl_xor(pd, m);
            }
            if (node < N) {
                hp[(size_t)node * 64 + chl] = f2bfu(hv);
                if (n16 == 0) {
                    a_src[(size_t)node * 8 + ct] = ps;
                    a_dst[(size_t)node * 8 + ct] = pd;
                }
            }
        }
    }
}

// ---------------------------------------------------------------------------
// Layer-1 aggregation, channel-split pass p (p=0: ch 0-63 / heads 0-3;
// p=1: ch 64-127 / heads 4-7). 6.4 MB gather footprint, 128 B rows. Two
// nodes per wave (32 lanes); lane u owns channels p*64+2u,2u+1. Per 32-edge
// chunk lane u computes 4 evs for edge u (coalesced a_src float4 gather)
// into per-wave LDS strips (wave-synchronous). Emits out1 as hi/lo
// packed-bf16 pairs for MFMA GEMM2.
// ---------------------------------------------------------------------------
__global__ __launch_bounds__(256) void k_aggr1(const int* __restrict__ rowptr,
                                               const int* __restrict__ cnt,
                                               const unsigned short* __restrict__ col,
                                               const float* __restrict__ a_src,
                                               const float* __restrict__ a_dst,
                                               const unsigned int* __restrict__ hp,
                                               const float* __restrict__ bias1,
                                               unsigned int* __restrict__ out1h,
                                               unsigned int* __restrict__ out1l, int N, int p) {
    __shared__ float evs[4][2][128];   // [wave][half][edge*4+head]
    __shared__ int   cls[4][2][32];    // [wave][half][edge]
    int t = threadIdx.x;
    int w = t >> 6;
    int lane = t & 63;
    int half = lane >> 5;
    int u = lane & 31;
    int node = blockIdx.x * 8 + w * 2 + half;
    bool nv = (node < N);
    int nodec = nv ? node : (N - 1);
    int beg = rowptr[nodec];
    int deg = nv ? cnt[nodec] : 0;
    int degO = __shfl_xor(deg, 32);
    int degmax = (deg > degO) ? deg : degO;
    if (degmax <= 0) return;   // uniform across wave

    int hh = u >> 3;                           // phase-local head 0..3
    float4 ad4 = *(const float4*)&a_dst[(size_t)nodec * 8 + p * 4];

    float* myev = &evs[w][half][0];
    int*   mycl = &cls[w][half][0];

    float den = 0.f, n0 = 0.f, n1 = 0.f;
    int c = 0;
    while (c < degmax) {
        int slot = c + u;
        int slotc = (slot < deg) ? slot : (deg - 1);
        if (slotc < 0) slotc = 0;
        int su = (int)col[beg + slotc];
        float4 as4 = *(const float4*)&a_src[(size_t)su * 8 + p * 4];
        bool valid = (slot < deg);
        float e0 = valid ? __expf(lrelu(as4.x + ad4.x)) : 0.f;
        float e1 = valid ? __expf(lrelu(as4.y + ad4.y)) : 0.f;
        float e2 = valid ? __expf(lrelu(as4.z + ad4.z)) : 0.f;
        float e3 = valid ? __expf(lrelu(as4.w + ad4.w)) : 0.f;
        *(float4*)&myev[u * 4] = make_float4(e0, e1, e2, e3);
        mycl[u] = su;
        // wave-synchronous LDS: single-wave producer/consumer, no barrier

        int ccm = degmax - c; ccm = (ccm < 32) ? ccm : 32;
        int sP = mycl[0];
        unsigned int uP = hp[sP * 32 + u];
        for (int i = 0; i < ccm; ++i) {
            int in = (i + 1 < ccm) ? (i + 1) : i;
            int sN = mycl[in];
            unsigned int uN = hp[sN * 32 + u];
            float ev = myev[i * 4 + hh];
            den += ev;
            n0 = fmaf(ev, bf_lo(uP), n0);
            n1 = fmaf(ev, bf_hi(uP), n1);
            uP = uN;
        }
        c += 32;
    }
    if (nv) {
        float inv = 1.f / (den + 1e-16f);
        int ch = p * 64 + 2 * u;
        float2 b = *(const float2*)&bias1[ch];
        float o0 = fmaf(n0, inv, b.x), o1 = fmaf(n1, inv, b.y);
        unsigned short h0 = f2bfu(o0), h1 = f2bfu(o1);
        float l0 = o0 - bfu2f(h0), l1 = o1 - bfu2f(h1);
        size_t idx = (size_t)node * 64 + p * 32 + u;
        out1h[idx] = (unsigned int)h0 | ((unsigned int)h1 << 16);
        out1l[idx] = (unsigned int)f2bfu(l0) | ((unsigned int)f2bfu(l1) << 16);
    }
}

// ---------------------------------------------------------------------------
// GEMM2 via MFMA: h2 = out1 @ W2 ([N,128]@[128,40->48]); out1 consumed as
// hi/lo bf16; 24 mfma. Emits bf16 h2 rows PADDED to 64 ushorts (128 B = one
// cacheline per row, R11 lesson) + fused fp32 a_src2/a_dst2.
// ---------------------------------------------------------------------------
__global__ __launch_bounds__(256) void k_gemm2(const unsigned int* __restrict__ out1h,
                                               const unsigned int* __restrict__ out1l,
                                               const bf16x8* __restrict__ W2p,
                                               const float* __restrict__ att_s2,
                                               const float* __restrict__ att_d2,
                                               unsigned short* __restrict__ h2s,
                                               float* __restrict__ a_src2,
                                               float* __restrict__ a_dst2, int N) {
    int t = threadIdx.x;
    int w = t >> 6, lane = t & 63, quad = lane >> 4, n16 = lane & 15;
    int row0 = blockIdx.x * 64 + w * 16;
    int arow = row0 + n16; if (arow >= N) arow = N - 1;

    bf16x8 ah[4], al[4];
#pragma unroll
    for (int c = 0; c < 4; ++c) {
        size_t base = (size_t)arow * 64 + (c * 32 + quad * 8) / 2;
        union { uint4 u; bf16x8 b; } hu, lu;
        hu.u = *(const uint4*)&out1h[base];
        lu.u = *(const uint4*)&out1l[base];
        ah[c] = hu.b;
        al[c] = lu.b;
    }

    f32x4 acc[3];
#pragma unroll
    for (int ct = 0; ct < 3; ++ct) acc[ct] = (f32x4){0.f, 0.f, 0.f, 0.f};

    const uint4* wp4 = (const uint4*)W2p;
#pragma unroll
    for (int ct = 0; ct < 3; ++ct) {
#pragma unroll
        for (int c = 0; c < 4; ++c) {
            union { uint4 u; bf16x8 b; } bu;
            bu.u = wp4[((ct * 4 + c) * 4 + quad) * 16 + n16];
            acc[ct] = __builtin_amdgcn_mfma_f32_16x16x32_bf16(ah[c], bu.b, acc[ct], 0, 0, 0);
            acc[ct] = __builtin_amdgcn_mfma_f32_16x16x32_bf16(al[c], bu.b, acc[ct], 0, 0, 0);
        }
    }

    float asv[3], adv[3];
#pragma unroll
    for (int ct = 0; ct < 3; ++ct) {
        int ch = ct * 16 + n16;
        asv[ct] = (ch < 40) ? att_s2[ch] : 0.f;
        adv[ct] = (ch < 40) ? att_d2[ch] : 0.f;
    }
    int nodeb = row0 + quad * 4;
#pragma unroll
    for (int reg = 0; reg < 4; ++reg) {
        int node = nodeb + reg;
        float ps = 0.f, pd = 0.f;
#pragma unroll
        for (int ct = 0; ct < 3; ++ct) {
            float hv = acc[ct][reg];
            ps = fmaf(hv, asv[ct], ps);
            pd = fmaf(hv, adv[ct], pd);
            int ch = ct * 16 + n16;
            if (node < N && ch < 40) h2s[(size_t)node * 64 + ch] = f2bfu(hv);
        }
#pragma unroll
        for (int m = 1; m < 16; m <<= 1) {
            ps += __shfl_xor(ps, m);
            pd += __shfl_xor(pd, m);
        }
        if (node < N && n16 == 0) {
            a_src2[node] = ps;
            a_dst2[node] = pd;
        }
    }
}

// ---------------------------------------------------------------------------
// Layer-2 aggregation (H=1, C=40). Two nodes per wave (32 lanes each); lane
// u<20 owns channels 2u,2u+1. h2 rows padded to 128 B -> each gather touches
// exactly one cacheline (6.4 MB footprint). Writes final output (+bias2).
// ---------------------------------------------------------------------------
__global__ __launch_bounds__(256) void k_aggr2(const int* __restrict__ rowptr,
                                               const int* __restrict__ cnt,
                                               const unsigned short* __restrict__ col,
                                               const float* __restrict__ a_src,
                                               const float* __restrict__ a_dst,
                                               const unsigned int* __restrict__ h2b,
                                               const float* __restrict__ bias2,
                                               float* __restrict__ out, int N) {
    __shared__ float evs[4][2][32];
    __shared__ int   cls[4][2][32];
    int t = threadIdx.x;
    int w = t >> 6;
    int lane = t & 63;
    int half = lane >> 5;
    int u = lane & 31;
    int node = blockIdx.x * 8 + w * 2 + half;
    bool nv = (node < N);
    int nodec = nv ? node : (N - 1);
    int beg = rowptr[nodec];
    int deg = nv ? cnt[nodec] : 0;
    int degO = __shfl_xor(deg, 32);
    int degmax = (deg > degO) ? deg : degO;
    if (degmax <= 0) return;

    int ucl = (u < 20) ? u : 19;
    float ad = a_dst[nodec];
    float* myev = &evs[w][half][0];
    int*   mycl = &cls[w][half][0];

    float den = 0.f, a0 = 0.f, a1 = 0.f;
    int c = 0;
    while (c < degmax) {
        int slot = c + u;
        int slotc = (slot < deg) ? slot : (deg - 1);
        if (slotc < 0) slotc = 0;
        int su = (int)col[beg + slotc];
        float ev = (slot < deg) ? __expf(lrelu(a_src[su] + ad)) : 0.f;
        myev[u] = ev;
        mycl[u] = su;

        int ccm = degmax - c; ccm = (ccm < 32) ? ccm : 32;
        int sP = mycl[0];
        unsigned int uP = h2b[sP * 32 + ucl];
        for (int i = 0; i < ccm; ++i) {
            int in = (i + 1 < ccm) ? (i + 1) : i;
            int sN = mycl[in];
            unsigned int uN = h2b[sN * 32 + ucl];
            float evv = myev[i];
            den += evv;
            a0 = fmaf(evv, bf_lo(uP), a0);
            a1 = fmaf(evv, bf_hi(uP), a1);
            uP = uN;
        }
        c += 32;
    }
    if (nv && u < 20) {
        float inv = 1.f / (den + 1e-16f);
        float2 b = *(const float2*)&bias2[2 * u];
        float2 o = make_float2(fmaf(a0, inv, b.x), fmaf(a1, inv, b.y));
        *(float2*)&out[(size_t)node * 40 + 2 * u] = o;
    }
}

// ---------------------------------------------------------------------------
extern "C" void kernel_launch(void* const* d_in, const int* in_sizes, int n_in,
                              void* d_out, int out_size, void* d_ws, size_t ws_size,
                              hipStream_t stream) {
    const float* x   = (const float*)d_in[0];
    const int*   ei  = (const int*)d_in[1];
    const float* W1  = (const float*)d_in[2];
    const float* as1 = (const float*)d_in[3];
    const float* ad1 = (const float*)d_in[4];
    const float* b1  = (const float*)d_in[5];
    const float* W2  = (const float*)d_in[6];
    const float* as2 = (const float*)d_in[7];
    const float* ad2 = (const float*)d_in[8];
    const float* b2  = (const float*)d_in[9];

    int N = in_sizes[0] / 128;
    int E = in_sizes[1] / 2;
    int EN = E + N;
    size_t Np = (size_t)((N + 3) & ~3);
    size_t ENp = ((size_t)EN + 3) & ~3;

    float* ws = (float*)d_ws;
    unsigned int* out1h = (unsigned int*)ws; ws += Np * 64;  // hi bf16 pairs
    unsigned int* out1l = (unsigned int*)ws; ws += Np * 64;  // lo bf16 pairs
    unsigned int* h1A = (unsigned int*)ws; ws += Np * 32;    // ch 0-63, bf16x2
    unsigned int* h1Bp = (unsigned int*)ws; ws += Np * 32;   // ch 64-127
    unsigned int* h2b = (unsigned int*)ws; ws += Np * 32;    // padded 128 B rows
    float* a_src1  = ws; ws += Np * 8;
    float* a_dst1  = ws; ws += Np * 8;
    float* a_src2v = ws; ws += Np;
    float* a_dst2v = ws; ws += Np;
    bf16x8* Wp  = (bf16x8*)ws; ws += 2048 * 4;               // 32 KB repacked W1
    bf16x8* W2p = (bf16x8*)ws; ws += 768 * 4;                // 12 KB repacked W2
    int* cnt    = (int*)ws; ws += Np;
    int* rowptr = (int*)ws; ws += Np;
    int* psum   = (int*)ws; ws += 256;
    unsigned short* col  = (unsigned short*)ws; ws += ENp / 2 + 4;
    unsigned short* rank = (unsigned short*)ws; ws += ENp / 2 + 4;

    int nb = (N + 1023) / 1024;  // scan blocks (<=256)
    int npre = (N > 2816 ? N : 2816);

    k_prep<<<(npre + 255) / 256, 256, 0, stream>>>(W1, Wp, W2, W2p, cnt, N);
    k_hist<<<(EN + 255) / 256, 256, 0, stream>>>(ei, E, N, cnt, rank);
    k_scan_part<<<nb, 256, 0, stream>>>(cnt, N, psum);
    k_scan_add<<<nb, 256, 0, stream>>>(cnt, N, psum, rowptr);
    k_scatter<<<(EN + 255) / 256, 256, 0, stream>>>(ei, E, N, rowptr, rank, col);

    k_gemm1<<<(N + 63) / 64, 256, 0, stream>>>(x, Wp, as1, ad1,
                                               (unsigned short*)h1A, (unsigned short*)h1Bp,
                                               a_src1, a_dst1, N);
    int nag = (N + 7) / 8;
    k_aggr1<<<nag, 256, 0, stream>>>(rowptr, cnt, col, a_src1, a_dst1, h1A, b1, out1h, out1l, N, 0);
    k_aggr1<<<nag, 256, 0, stream>>>(rowptr, cnt, col, a_src1, a_dst1, h1Bp, b1, out1h, out1l, N, 1);
    k_gemm2<<<(N + 63) / 64, 256, 0, stream>>>(out1h, out1l, W2p, as2, ad2,
                                               (unsigned short*)h2b, a_src2v, a_dst2v, N);
    k_aggr2<<<nag, 256, 0, stream>>>(rowptr, cnt, col, a_src2v, a_dst2v, h2b, b2, (float*)d_out, N);
}

// Round 15
// 237.462 us; speedup vs baseline: 1.3137x; 1.0231x over previous
//
#include <hip/hip_runtime.h>
#include <hip/hip_bf16.h>
#include <math.h>

#define NEG_SLOPE 0.2f

typedef __bf16 bf16x8 __attribute__((ext_vector_type(8)));
typedef float f32x4 __attribute__((ext_vector_type(4)));

__device__ __forceinline__ float lrelu(float x) { return x > 0.f ? x : NEG_SLOPE * x; }

__device__ __forceinline__ unsigned short f2bfu(float f) {
    unsigned int ua = __float_as_uint(f);
    return (unsigned short)((ua + 0x7fffu + ((ua >> 16) & 1u)) >> 16);
}
__device__ __forceinline__ float bfu2f(unsigned short u) {
    return __uint_as_float(((unsigned int)u) << 16);
}
__device__ __forceinline__ float bf_lo(unsigned int u) { return __uint_as_float(u << 16); }
__device__ __forceinline__ float bf_hi(unsigned int u) { return __uint_as_float(u & 0xffff0000u); }

// ---------------------------------------------------------------------------
// prep: zero cnt + repack W1 (2048 frags) + repack W2 (768 frags, pad 40->48)
// ---------------------------------------------------------------------------
__global__ __launch_bounds__(256) void k_prep(const float* __restrict__ W1,
                                              bf16x8* __restrict__ Wp,
                                              const float* __restrict__ W2,
                                              bf16x8* __restrict__ W2p,
                                              int* __restrict__ cnt, int N) {
    int g = blockIdx.x * 256 + threadIdx.x;
    if (g < 2048) {
        int n = g & 15, quad = (g >> 4) & 3, c = (g >> 6) & 3, ct = g >> 8;
        bf16x8 v;
#pragma unroll
        for (int j = 0; j < 8; ++j)
            v[j] = (__bf16)W1[(c * 32 + quad * 8 + j) * 128 + ct * 16 + n];
        Wp[g] = v;
    } else if (g < 2816) {
        int idx = g - 2048;
        int n = idx & 15, quad = (idx >> 4) & 3, c = (idx >> 6) & 3, ct = idx >> 8;
        int colc = ct * 16 + n;
        bf16x8 v;
#pragma unroll
        for (int j = 0; j < 8; ++j)
            v[j] = (colc < 40) ? (__bf16)W2[(c * 32 + quad * 8 + j) * 40 + colc] : (__bf16)0.f;
        W2p[idx] = v;
    }
    if (g < N) cnt[g] = 0;
}

// ---------------------------------------------------------------------------
// histogram of dst (incl. self-loops); emits rank[e] (ushort: max deg small)
// ---------------------------------------------------------------------------
__global__ __launch_bounds__(256) void k_hist(const int* __restrict__ ei, int E, int N,
                                              int* __restrict__ cnt,
                                              unsigned short* __restrict__ rank) {
    int e = blockIdx.x * 256 + threadIdx.x;
    if (e >= E + N) return;
    int d = (e < E) ? ei[E + e] : (e - E);
    rank[e] = (unsigned short)atomicAdd(&cnt[d], 1);
}

// ---------------------------------------------------------------------------
// 2-stage exclusive scan of cnt[N] -> rowptr[N]; chunk = 1024 per block.
// Stage B inlines the per-block psum prefix (nb <= 256, L2-hot scalar loop).
// ---------------------------------------------------------------------------
__global__ __launch_bounds__(256) void k_scan_part(const int* __restrict__ cnt, int N,
                                                   int* __restrict__ psum) {
    __shared__ int sh[256];
    int t = threadIdx.x;
    int base = blockIdx.x * 1024 + t * 4;
    int tl = 0;
#pragma unroll
    for (int j = 0; j < 4; ++j) tl += (base + j < N) ? cnt[base + j] : 0;
    sh[t] = tl; __syncthreads();
    for (int off = 128; off > 0; off >>= 1) {
        if (t < off) sh[t] += sh[t + off];
        __syncthreads();
    }
    if (t == 0) psum[blockIdx.x] = sh[0];
}

__global__ __launch_bounds__(256) void k_scan_add(const int* __restrict__ cnt, int N,
                                                  const int* __restrict__ psum,
                                                  int* __restrict__ rowptr) {
    __shared__ int sh[256];
    __shared__ int basep;
    int t = threadIdx.x;
    if (t == 0) {
        int s = 0;
        for (int i = 0; i < blockIdx.x; ++i) s += psum[i];
        basep = s;
    }
    int base = blockIdx.x * 1024 + t * 4;
    int c[4]; int tl = 0;
#pragma unroll
    for (int j = 0; j < 4; ++j) { c[j] = (base + j < N) ? cnt[base + j] : 0; tl += c[j]; }
    sh[t] = tl; __syncthreads();
    for (int off = 1; off < 256; off <<= 1) {
        int a = (t >= off) ? sh[t - off] : 0;
        __syncthreads();
        sh[t] += a;
        __syncthreads();
    }
    int run = basep + (sh[t] - tl);
#pragma unroll
    for (int j = 0; j < 4; ++j) {
        if (base + j < N) { rowptr[base + j] = run; run += c[j]; }
    }
}

// ---------------------------------------------------------------------------
// scatter src into CSR by dst using precomputed rank (no atomics); col ushort
// ---------------------------------------------------------------------------
__global__ __launch_bounds__(256) void k_scatter(const int* __restrict__ ei, int E, int N,
                                                 const int* __restrict__ rowptr,
                                                 const unsigned short* __restrict__ rank,
                                                 unsigned short* __restrict__ col) {
    int e = blockIdx.x * 256 + threadIdx.x;
    if (e >= E + N) return;
    int s, d;
    if (e < E) { s = ei[e]; d = ei[E + e]; } else { s = d = e - E; }
    col[rowptr[d] + (int)rank[e]] = (unsigned short)s;
}

// ---------------------------------------------------------------------------
// GEMM1 via MFMA: h1 = x @ W1. One wave = 16 rows x 128 cols; x split hi/lo
// bf16; 64 mfma. No LDS. Emits channel-split packed-bf16 h1A/h1B (128 B rows
// = one cacheline) + fused fp32 a_src1/a_dst1.
// ---------------------------------------------------------------------------
__global__ __launch_bounds__(256) void k_gemm1(const float* __restrict__ x,
                                               const bf16x8* __restrict__ Wp,
                                               const float* __restrict__ att_s,
                                               const float* __restrict__ att_d,
                                               unsigned short* __restrict__ h1A,
                                               unsigned short* __restrict__ h1B,
                                               float* __restrict__ a_src,
                                               float* __restrict__ a_dst, int N) {
    int t = threadIdx.x;
    int w = t >> 6, lane = t & 63, quad = lane >> 4, n16 = lane & 15;
    int row0 = blockIdx.x * 64 + w * 16;
    int arow = row0 + n16; if (arow >= N) arow = N - 1;
    const float* px = x + (size_t)arow * 128;

    bf16x8 ah[4], al[4];
#pragma unroll
    for (int c = 0; c < 4; ++c) {
        float4 v0 = *(const float4*)&px[c * 32 + quad * 8];
        float4 v1 = *(const float4*)&px[c * 32 + quad * 8 + 4];
        float xf[8] = {v0.x, v0.y, v0.z, v0.w, v1.x, v1.y, v1.z, v1.w};
#pragma unroll
        for (int j = 0; j < 8; ++j) {
            __bf16 hi = (__bf16)xf[j];
            ah[c][j] = hi;
            al[c][j] = (__bf16)(xf[j] - (float)hi);
        }
    }

    f32x4 acc[8];
#pragma unroll
    for (int ct = 0; ct < 8; ++ct) acc[ct] = (f32x4){0.f, 0.f, 0.f, 0.f};

    const uint4* wp4 = (const uint4*)Wp;
#pragma unroll
    for (int ct = 0; ct < 8; ++ct) {
#pragma unroll
        for (int c = 0; c < 4; ++c) {
            union { uint4 u; bf16x8 b; } bu;
            bu.u = wp4[((ct * 4 + c) * 4 + quad) * 16 + n16];
            acc[ct] = __builtin_amdgcn_mfma_f32_16x16x32_bf16(ah[c], bu.b, acc[ct], 0, 0, 0);
            acc[ct] = __builtin_amdgcn_mfma_f32_16x16x32_bf16(al[c], bu.b, acc[ct], 0, 0, 0);
        }
    }

    float asv[8], adv[8];
#pragma unroll
    for (int ct = 0; ct < 8; ++ct) {
        asv[ct] = att_s[ct * 16 + n16];
        adv[ct] = att_d[ct * 16 + n16];
    }
    int nodeb = row0 + quad * 4;
#pragma unroll
    for (int ct = 0; ct < 8; ++ct) {
        unsigned short* hp = (ct < 4) ? h1A : h1B;
        int chl = (ct & 3) * 16 + n16;
#pragma unroll
        for (int reg = 0; reg < 4; ++reg) {
            int node = nodeb + reg;
            float hv = acc[ct][reg];
            float ps = hv * asv[ct];
            float pd = hv * adv[ct];
#pragma unroll
            for (int m = 1; m < 16; m <<= 1) {
                ps += __shfl_xor(ps, m);
                pd += __shfl_xor(pd, m);
            }
            if (node < N) {
                hp[(size_t)node * 64 + chl] = f2bfu(hv);
                if (n16 == 0) {
                    a_src[(size_t)node * 8 + ct] = ps;
                    a_dst[(size_t)node * 8 + ct] = pd;
                }
            }
        }
    }
}

// ---------------------------------------------------------------------------
// Layer-1 aggregation, both channel halves in ONE launch: blocks [0,nag) do
// p=0 (ch 0-63), blocks [nag,2*nag) do p=1 (ch 64-127) — dispatch order keeps
// per-half L2 locality. Two nodes per wave (32 lanes); lane u owns channels
// p*64+2u,2u+1. Per 32-edge chunk lane u computes 4 evs for edge u into
// per-wave LDS strips (wave-synchronous). DEPTH-3 prefetch on the h-gather
// (3 VMEM in flight/wave: latency-bound loop). Emits out1 hi/lo bf16 pairs.
// ---------------------------------------------------------------------------
__global__ __launch_bounds__(256) void k_aggr1(const int* __restrict__ rowptr,
                                               const int* __restrict__ cnt,
                                               const unsigned short* __restrict__ col,
                                               const float* __restrict__ a_src,
                                               const float* __restrict__ a_dst,
                                               const unsigned int* __restrict__ h1A,
                                               const unsigned int* __restrict__ h1B,
                                               const float* __restrict__ bias1,
                                               unsigned int* __restrict__ out1h,
                                               unsigned int* __restrict__ out1l,
                                               int N, int nag) {
    __shared__ float evs[4][2][128];   // [wave][half][edge*4+head]
    __shared__ int   cls[4][2][32];    // [wave][half][edge]
    int p = (blockIdx.x >= nag) ? 1 : 0;
    int blk = blockIdx.x - p * nag;
    const unsigned int* hp = p ? h1B : h1A;
    int t = threadIdx.x;
    int w = t >> 6;
    int lane = t & 63;
    int half = lane >> 5;
    int u = lane & 31;
    int node = blk * 8 + w * 2 + half;
    bool nv = (node < N);
    int nodec = nv ? node : (N - 1);
    int beg = rowptr[nodec];
    int deg = nv ? cnt[nodec] : 0;
    int degO = __shfl_xor(deg, 32);
    int degmax = (deg > degO) ? deg : degO;
    if (degmax <= 0) return;   // uniform across wave

    int hh = u >> 3;                           // phase-local head 0..3
    float4 ad4 = *(const float4*)&a_dst[(size_t)nodec * 8 + p * 4];

    float* myev = &evs[w][half][0];
    int*   mycl = &cls[w][half][0];

    float den = 0.f, n0 = 0.f, n1 = 0.f;
    int c = 0;
    while (c < degmax) {
        int slot = c + u;
        int slotc = (slot < deg) ? slot : (deg - 1);
        if (slotc < 0) slotc = 0;
        int su = (int)col[beg + slotc];
        float4 as4 = *(const float4*)&a_src[(size_t)su * 8 + p * 4];
        bool valid = (slot < deg);
        float e0 = valid ? __expf(lrelu(as4.x + ad4.x)) : 0.f;
        float e1 = valid ? __expf(lrelu(as4.y + ad4.y)) : 0.f;
        float e2 = valid ? __expf(lrelu(as4.z + ad4.z)) : 0.f;
        float e3 = valid ? __expf(lrelu(as4.w + ad4.w)) : 0.f;
        *(float4*)&myev[u * 4] = make_float4(e0, e1, e2, e3);
        mycl[u] = su;
        // wave-synchronous LDS: single-wave producer/consumer, no barrier

        int ccm = degmax - c; ccm = (ccm < 32) ? ccm : 32;
        int last = ccm - 1;
        // depth-3 pipeline on the h-gather
        int s0 = mycl[0];
        unsigned int u0 = hp[s0 * 32 + u];
        int i1 = (1 < last) ? 1 : last;
        int s1 = mycl[i1];
        unsigned int u1 = hp[s1 * 32 + u];
        int i2 = (2 < last) ? 2 : last;
        int s2 = mycl[i2];
        unsigned int u2 = hp[s2 * 32 + u];
        for (int i = 0; i < ccm; ++i) {
            int iN = i + 3; iN = (iN < last) ? iN : last;
            int sN = mycl[iN];
            unsigned int uN = hp[sN * 32 + u];
            float ev = myev[i * 4 + hh];
            den += ev;
            n0 = fmaf(ev, bf_lo(u0), n0);
            n1 = fmaf(ev, bf_hi(u0), n1);
            u0 = u1; u1 = u2; u2 = uN;
        }
        c += 32;
    }
    if (nv) {
        float inv = 1.f / (den + 1e-16f);
        int ch = p * 64 + 2 * u;
        float2 b = *(const float2*)&bias1[ch];
        float o0 = fmaf(n0, inv, b.x), o1 = fmaf(n1, inv, b.y);
        unsigned short h0 = f2bfu(o0), h1 = f2bfu(o1);
        float l0 = o0 - bfu2f(h0), l1 = o1 - bfu2f(h1);
        size_t idx = (size_t)node * 64 + p * 32 + u;
        out1h[idx] = (unsigned int)h0 | ((unsigned int)h1 << 16);
        out1l[idx] = (unsigned int)f2bfu(l0) | ((unsigned int)f2bfu(l1) << 16);
    }
}

// ---------------------------------------------------------------------------
// GEMM2 via MFMA: h2 = out1 @ W2 ([N,128]@[128,40->48]); out1 consumed as
// hi/lo bf16; 24 mfma. Emits bf16 h2 rows padded to 64 ushorts (one
// cacheline per row) + fused fp32 a_src2/a_dst2.
// ---------------------------------------------------------------------------
__global__ __launch_bounds__(256) void k_gemm2(const unsigned int* __restrict__ out1h,
                                               const unsigned int* __restrict__ out1l,
                                               const bf16x8* __restrict__ W2p,
                                               const float* __restrict__ att_s2,
                                               const float* __restrict__ att_d2,
                                               unsigned short* __restrict__ h2s,
                                               float* __restrict__ a_src2,
                                               float* __restrict__ a_dst2, int N) {
    int t = threadIdx.x;
    int w = t >> 6, lane = t & 63, quad = lane >> 4, n16 = lane & 15;
    int row0 = blockIdx.x * 64 + w * 16;
    int arow = row0 + n16; if (arow >= N) arow = N - 1;

    bf16x8 ah[4], al[4];
#pragma unroll
    for (int c = 0; c < 4; ++c) {
        size_t base = (size_t)arow * 64 + (c * 32 + quad * 8) / 2;
        union { uint4 u; bf16x8 b; } hu, lu;
        hu.u = *(const uint4*)&out1h[base];
        lu.u = *(const uint4*)&out1l[base];
        ah[c] = hu.b;
        al[c] = lu.b;
    }

    f32x4 acc[3];
#pragma unroll
    for (int ct = 0; ct < 3; ++ct) acc[ct] = (f32x4){0.f, 0.f, 0.f, 0.f};

    const uint4* wp4 = (const uint4*)W2p;
#pragma unroll
    for (int ct = 0; ct < 3; ++ct) {
#pragma unroll
        for (int c = 0; c < 4; ++c) {
            union { uint4 u; bf16x8 b; } bu;
            bu.u = wp4[((ct * 4 + c) * 4 + quad) * 16 + n16];
            acc[ct] = __builtin_amdgcn_mfma_f32_16x16x32_bf16(ah[c], bu.b, acc[ct], 0, 0, 0);
            acc[ct] = __builtin_amdgcn_mfma_f32_16x16x32_bf16(al[c], bu.b, acc[ct], 0, 0, 0);
        }
    }

    float asv[3], adv[3];
#pragma unroll
    for (int ct = 0; ct < 3; ++ct) {
        int ch = ct * 16 + n16;
        asv[ct] = (ch < 40) ? att_s2[ch] : 0.f;
        adv[ct] = (ch < 40) ? att_d2[ch] : 0.f;
    }
    int nodeb = row0 + quad * 4;
#pragma unroll
    for (int reg = 0; reg < 4; ++reg) {
        int node = nodeb + reg;
        float ps = 0.f, pd = 0.f;
#pragma unroll
        for (int ct = 0; ct < 3; ++ct) {
            float hv = acc[ct][reg];
            ps = fmaf(hv, asv[ct], ps);
            pd = fmaf(hv, adv[ct], pd);
            int ch = ct * 16 + n16;
            if (node < N && ch < 40) h2s[(size_t)node * 64 + ch] = f2bfu(hv);
        }
#pragma unroll
        for (int m = 1; m < 16; m <<= 1) {
            ps += __shfl_xor(ps, m);
            pd += __shfl_xor(pd, m);
        }
        if (node < N && n16 == 0) {
            a_src2[node] = ps;
            a_dst2[node] = pd;
        }
    }
}

// ---------------------------------------------------------------------------
// Layer-2 aggregation (H=1, C=40). Two nodes per wave (32 lanes each); lane
// u<20 owns channels 2u,2u+1; h2 rows = one cacheline. DEPTH-3 prefetch on
// the h-gather. Writes final output (+bias2) directly.
// ---------------------------------------------------------------------------
__global__ __launch_bounds__(256) void k_aggr2(const int* __restrict__ rowptr,
                                               const int* __restrict__ cnt,
                                               const unsigned short* __restrict__ col,
                                               const float* __restrict__ a_src,
                                               const float* __restrict__ a_dst,
                                               const unsigned int* __restrict__ h2b,
                                               const float* __restrict__ bias2,
                                               float* __restrict__ out, int N) {
    __shared__ float evs[4][2][32];
    __shared__ int   cls[4][2][32];
    int t = threadIdx.x;
    int w = t >> 6;
    int lane = t & 63;
    int half = lane >> 5;
    int u = lane & 31;
    int node = blockIdx.x * 8 + w * 2 + half;
    bool nv = (node < N);
    int nodec = nv ? node : (N - 1);
    int beg = rowptr[nodec];
    int deg = nv ? cnt[nodec] : 0;
    int degO = __shfl_xor(deg, 32);
    int degmax = (deg > degO) ? deg : degO;
    if (degmax <= 0) return;

    int ucl = (u < 20) ? u : 19;
    float ad = a_dst[nodec];
    float* myev = &evs[w][half][0];
    int*   mycl = &cls[w][half][0];

    float den = 0.f, a0 = 0.f, a1 = 0.f;
    int c = 0;
    while (c < degmax) {
        int slot = c + u;
        int slotc = (slot < deg) ? slot : (deg - 1);
        if (slotc < 0) slotc = 0;
        int su = (int)col[beg + slotc];
        float ev = (slot < deg) ? __expf(lrelu(a_src[su] + ad)) : 0.f;
        myev[u] = ev;
        mycl[u] = su;

        int ccm = degmax - c; ccm = (ccm < 32) ? ccm : 32;
        int last = ccm - 1;
        int s0 = mycl[0];
        unsigned int u0 = h2b[s0 * 32 + ucl];
        int i1 = (1 < last) ? 1 : last;
        int s1 = mycl[i1];
        unsigned int u1 = h2b[s1 * 32 + ucl];
        int i2 = (2 < last) ? 2 : last;
        int s2 = mycl[i2];
        unsigned int u2 = h2b[s2 * 32 + ucl];
        for (int i = 0; i < ccm; ++i) {
            int iN = i + 3; iN = (iN < last) ? iN : last;
            int sN = mycl[iN];
            unsigned int uN = h2b[sN * 32 + ucl];
            float evv = myev[i];
            den += evv;
            a0 = fmaf(evv, bf_lo(u0), a0);
            a1 = fmaf(evv, bf_hi(u0), a1);
            u0 = u1; u1 = u2; u2 = uN;
        }
        c += 32;
    }
    if (nv && u < 20) {
        float inv = 1.f / (den + 1e-16f);
        float2 b = *(const float2*)&bias2[2 * u];
        float2 o = make_float2(fmaf(a0, inv, b.x), fmaf(a1, inv, b.y));
        *(float2*)&out[(size_t)node * 40 + 2 * u] = o;
    }
}

// ---------------------------------------------------------------------------
extern "C" void kernel_launch(void* const* d_in, const int* in_sizes, int n_in,
                              void* d_out, int out_size, void* d_ws, size_t ws_size,
                              hipStream_t stream) {
    const float* x   = (const float*)d_in[0];
    const int*   ei  = (const int*)d_in[1];
    const float* W1  = (const float*)d_in[2];
    const float* as1 = (const float*)d_in[3];
    const float* ad1 = (const float*)d_in[4];
    const float* b1  = (const float*)d_in[5];
    const float* W2  = (const float*)d_in[6];
    const float* as2 = (const float*)d_in[7];
    const float* ad2 = (const float*)d_in[8];
    const float* b2  = (const float*)d_in[9];

    int N = in_sizes[0] / 128;
    int E = in_sizes[1] / 2;
    int EN = E + N;
    size_t Np = (size_t)((N + 3) & ~3);
    size_t ENp = ((size_t)EN + 3) & ~3;

    float* ws = (float*)d_ws;
    unsigned int* out1h = (unsigned int*)ws; ws += Np * 64;  // hi bf16 pairs
    unsigned int* out1l = (unsigned int*)ws; ws += Np * 64;  // lo bf16 pairs
    unsigned int* h1A = (unsigned int*)ws; ws += Np * 32;    // ch 0-63, bf16x2
    unsigned int* h1Bp = (unsigned int*)ws; ws += Np * 32;   // ch 64-127
    unsigned int* h2b = (unsigned int*)ws; ws += Np * 32;    // padded 128 B rows
    float* a_src1  = ws; ws += Np * 8;
    float* a_dst1  = ws; ws += Np * 8;
    float* a_src2v = ws; ws += Np;
    float* a_dst2v = ws; ws += Np;
    bf16x8* Wp  = (bf16x8*)ws; ws += 2048 * 4;               // 32 KB repacked W1
    bf16x8* W2p = (bf16x8*)ws; ws += 768 * 4;                // 12 KB repacked W2
    int* cnt    = (int*)ws; ws += Np;
    int* rowptr = (int*)ws; ws += Np;
    int* psum   = (int*)ws; ws += 256;
    unsigned short* col  = (unsigned short*)ws; ws += ENp / 2 + 4;
    unsigned short* rank = (unsigned short*)ws; ws += ENp / 2 + 4;

    int nb = (N + 1023) / 1024;  // scan blocks (<=256)
    int npre = (N > 2816 ? N : 2816);

    k_prep<<<(npre + 255) / 256, 256, 0, stream>>>(W1, Wp, W2, W2p, cnt, N);
    k_hist<<<(EN + 255) / 256, 256, 0, stream>>>(ei, E, N, cnt, rank);
    k_scan_part<<<nb, 256, 0, stream>>>(cnt, N, psum);
    k_scan_add<<<nb, 256, 0, stream>>>(cnt, N, psum, rowptr);
    k_scatter<<<(EN + 255) / 256, 256, 0, stream>>>(ei, E, N, rowptr, rank, col);

    k_gemm1<<<(N + 63) / 64, 256, 0, stream>>>(x, Wp, as1, ad1,
                                               (unsigned short*)h1A, (unsigned short*)h1Bp,
                                               a_src1, a_dst1, N);
    int nag = (N + 7) / 8;
    k_aggr1<<<2 * nag, 256, 0, stream>>>(rowptr, cnt, col, a_src1, a_dst1,
                                         h1A, h1Bp, b1, out1h, out1l, N, nag);
    k_gemm2<<<(N + 63) / 64, 256, 0, stream>>>(out1h, out1l, W2p, as2, ad2,
                                               (unsigned short*)h2b, a_src2v, a_dst2v, N);
    k_aggr2<<<nag, 256, 0, stream>>>(rowptr, cnt, col, a_src2v, a_dst2v, h2b, b2, (float*)d_out, N);
}

// Round 16
// 235.473 us; speedup vs baseline: 1.3248x; 1.0084x over previous
//
#include <hip/hip_runtime.h>
#include <hip/hip_bf16.h>
#include <math.h>

#define NEG_SLOPE 0.2f

typedef __bf16 bf16x8 __attribute__((ext_vector_type(8)));
typedef float f32x4 __attribute__((ext_vector_type(4)));

__device__ __forceinline__ float lrelu(float x) { return x > 0.f ? x : NEG_SLOPE * x; }

__device__ __forceinline__ unsigned short f2bfu(float f) {
    unsigned int ua = __float_as_uint(f);
    return (unsigned short)((ua + 0x7fffu + ((ua >> 16) & 1u)) >> 16);
}
__device__ __forceinline__ float bfu2f(unsigned short u) {
    return __uint_as_float(((unsigned int)u) << 16);
}
__device__ __forceinline__ float bf_lo(unsigned int u) { return __uint_as_float(u << 16); }
__device__ __forceinline__ float bf_hi(unsigned int u) { return __uint_as_float(u & 0xffff0000u); }

// ---------------------------------------------------------------------------
// prep: zero cnt + repack W1 (2048 frags) + repack W2 (768 frags, pad 40->48)
// ---------------------------------------------------------------------------
__global__ __launch_bounds__(256) void k_prep(const float* __restrict__ W1,
                                              bf16x8* __restrict__ Wp,
                                              const float* __restrict__ W2,
                                              bf16x8* __restrict__ W2p,
                                              int* __restrict__ cnt, int N) {
    int g = blockIdx.x * 256 + threadIdx.x;
    if (g < 2048) {
        int n = g & 15, quad = (g >> 4) & 3, c = (g >> 6) & 3, ct = g >> 8;
        bf16x8 v;
#pragma unroll
        for (int j = 0; j < 8; ++j)
            v[j] = (__bf16)W1[(c * 32 + quad * 8 + j) * 128 + ct * 16 + n];
        Wp[g] = v;
    } else if (g < 2816) {
        int idx = g - 2048;
        int n = idx & 15, quad = (idx >> 4) & 3, c = (idx >> 6) & 3, ct = idx >> 8;
        int colc = ct * 16 + n;
        bf16x8 v;
#pragma unroll
        for (int j = 0; j < 8; ++j)
            v[j] = (colc < 40) ? (__bf16)W2[(c * 32 + quad * 8 + j) * 40 + colc] : (__bf16)0.f;
        W2p[idx] = v;
    }
    if (g < N) cnt[g] = 0;
}

// ---------------------------------------------------------------------------
// histogram of dst (incl. self-loops); emits rank[e] (ushort: max deg small)
// ---------------------------------------------------------------------------
__global__ __launch_bounds__(256) void k_hist(const int* __restrict__ ei, int E, int N,
                                              int* __restrict__ cnt,
                                              unsigned short* __restrict__ rank) {
    int e = blockIdx.x * 256 + threadIdx.x;
    if (e >= E + N) return;
    int d = (e < E) ? ei[E + e] : (e - E);
    rank[e] = (unsigned short)atomicAdd(&cnt[d], 1);
}

// ---------------------------------------------------------------------------
// 2-stage exclusive scan of cnt[N] -> rowptr[N]; chunk = 1024 per block.
// Stage B inlines the per-block psum prefix (nb <= 256, L2-hot scalar loop).
// ---------------------------------------------------------------------------
__global__ __launch_bounds__(256) void k_scan_part(const int* __restrict__ cnt, int N,
                                                   int* __restrict__ psum) {
    __shared__ int sh[256];
    int t = threadIdx.x;
    int base = blockIdx.x * 1024 + t * 4;
    int tl = 0;
#pragma unroll
    for (int j = 0; j < 4; ++j) tl += (base + j < N) ? cnt[base + j] : 0;
    sh[t] = tl; __syncthreads();
    for (int off = 128; off > 0; off >>= 1) {
        if (t < off) sh[t] += sh[t + off];
        __syncthreads();
    }
    if (t == 0) psum[blockIdx.x] = sh[0];
}

__global__ __launch_bounds__(256) void k_scan_add(const int* __restrict__ cnt, int N,
                                                  const int* __restrict__ psum,
                                                  int* __restrict__ rowptr) {
    __shared__ int sh[256];
    __shared__ int basep;
    int t = threadIdx.x;
    if (t == 0) {
        int s = 0;
        for (int i = 0; i < blockIdx.x; ++i) s += psum[i];
        basep = s;
    }
    int base = blockIdx.x * 1024 + t * 4;
    int c[4]; int tl = 0;
#pragma unroll
    for (int j = 0; j < 4; ++j) { c[j] = (base + j < N) ? cnt[base + j] : 0; tl += c[j]; }
    sh[t] = tl; __syncthreads();
    for (int off = 1; off < 256; off <<= 1) {
        int a = (t >= off) ? sh[t - off] : 0;
        __syncthreads();
        sh[t] += a;
        __syncthreads();
    }
    int run = basep + (sh[t] - tl);
#pragma unroll
    for (int j = 0; j < 4; ++j) {
        if (base + j < N) { rowptr[base + j] = run; run += c[j]; }
    }
}

// ---------------------------------------------------------------------------
// scatter src into CSR by dst using precomputed rank (no atomics); col ushort
// ---------------------------------------------------------------------------
__global__ __launch_bounds__(256) void k_scatter(const int* __restrict__ ei, int E, int N,
                                                 const int* __restrict__ rowptr,
                                                 const unsigned short* __restrict__ rank,
                                                 unsigned short* __restrict__ col) {
    int e = blockIdx.x * 256 + threadIdx.x;
    if (e >= E + N) return;
    int s, d;
    if (e < E) { s = ei[e]; d = ei[E + e]; } else { s = d = e - E; }
    col[rowptr[d] + (int)rank[e]] = (unsigned short)s;
}

// ---------------------------------------------------------------------------
// GEMM1 via MFMA: h1 = x @ W1. One wave = 16 rows x 128 cols; x split hi/lo
// bf16; 64 mfma. No LDS. Emits channel-split packed-bf16 h1A/h1B (128 B rows
// = one cacheline) + fused fp32 a_src1/a_dst1.
// ---------------------------------------------------------------------------
__global__ __launch_bounds__(256) void k_gemm1(const float* __restrict__ x,
                                               const bf16x8* __restrict__ Wp,
                                               const float* __restrict__ att_s,
                                               const float* __restrict__ att_d,
                                               unsigned short* __restrict__ h1A,
                                               unsigned short* __restrict__ h1B,
                                               float* __restrict__ a_src,
                                               float* __restrict__ a_dst, int N) {
    int t = threadIdx.x;
    int w = t >> 6, lane = t & 63, quad = lane >> 4, n16 = lane & 15;
    int row0 = blockIdx.x * 64 + w * 16;
    int arow = row0 + n16; if (arow >= N) arow = N - 1;
    const float* px = x + (size_t)arow * 128;

    bf16x8 ah[4], al[4];
#pragma unroll
    for (int c = 0; c < 4; ++c) {
        float4 v0 = *(const float4*)&px[c * 32 + quad * 8];
        float4 v1 = *(const float4*)&px[c * 32 + quad * 8 + 4];
        float xf[8] = {v0.x, v0.y, v0.z, v0.w, v1.x, v1.y, v1.z, v1.w};
#pragma unroll
        for (int j = 0; j < 8; ++j) {
            __bf16 hi = (__bf16)xf[j];
            ah[c][j] = hi;
            al[c][j] = (__bf16)(xf[j] - (float)hi);
        }
    }

    f32x4 acc[8];
#pragma unroll
    for (int ct = 0; ct < 8; ++ct) acc[ct] = (f32x4){0.f, 0.f, 0.f, 0.f};

    const uint4* wp4 = (const uint4*)Wp;
#pragma unroll
    for (int ct = 0; ct < 8; ++ct) {
#pragma unroll
        for (int c = 0; c < 4; ++c) {
            union { uint4 u; bf16x8 b; } bu;
            bu.u = wp4[((ct * 4 + c) * 4 + quad) * 16 + n16];
            acc[ct] = __builtin_amdgcn_mfma_f32_16x16x32_bf16(ah[c], bu.b, acc[ct], 0, 0, 0);
            acc[ct] = __builtin_amdgcn_mfma_f32_16x16x32_bf16(al[c], bu.b, acc[ct], 0, 0, 0);
        }
    }

    float asv[8], adv[8];
#pragma unroll
    for (int ct = 0; ct < 8; ++ct) {
        asv[ct] = att_s[ct * 16 + n16];
        adv[ct] = att_d[ct * 16 + n16];
    }
    int nodeb = row0 + quad * 4;
#pragma unroll
    for (int ct = 0; ct < 8; ++ct) {
        unsigned short* hp = (ct < 4) ? h1A : h1B;
        int chl = (ct & 3) * 16 + n16;
#pragma unroll
        for (int reg = 0; reg < 4; ++reg) {
            int node = nodeb + reg;
            float hv = acc[ct][reg];
            float ps = hv * asv[ct];
            float pd = hv * adv[ct];
#pragma unroll
            for (int m = 1; m < 16; m <<= 1) {
                ps += __shfl_xor(ps, m);
                pd += __shfl_xor(pd, m);
            }
            if (node < N) {
                hp[(size_t)node * 64 + chl] = f2bfu(hv);
                if (n16 == 0) {
                    a_src[(size_t)node * 8 + ct] = ps;
                    a_dst[(size_t)node * 8 + ct] = pd;
                }
            }
        }
    }
}

// ---------------------------------------------------------------------------
// Layer-1 aggregation, both channel halves in ONE launch: blocks [0,nag) do
// p=0, blocks [nag,2*nag) do p=1. Two nodes per wave (32 lanes); lane u owns
// channels p*64+2u,2u+1. Per 32-edge chunk lane u computes 4 evs for edge u
// into per-wave LDS strips (wave-synchronous). Depth-3 prefetch with
// UNCLAMPED unrolled body + load-free 3-iter drain tail (VALU-issue-bound
// loop: kills the per-iter min-clamp and pipeline moves).
// ---------------------------------------------------------------------------
__global__ __launch_bounds__(256) void k_aggr1(const int* __restrict__ rowptr,
                                               const int* __restrict__ cnt,
                                               const unsigned short* __restrict__ col,
                                               const float* __restrict__ a_src,
                                               const float* __restrict__ a_dst,
                                               const unsigned int* __restrict__ h1A,
                                               const unsigned int* __restrict__ h1B,
                                               const float* __restrict__ bias1,
                                               unsigned int* __restrict__ out1h,
                                               unsigned int* __restrict__ out1l,
                                               int N, int nag) {
    __shared__ float evs[4][2][128];   // [wave][half][edge*4+head]
    __shared__ int   cls[4][2][32];    // [wave][half][edge]
    int p = (blockIdx.x >= nag) ? 1 : 0;
    int blk = blockIdx.x - p * nag;
    const unsigned int* hp = p ? h1B : h1A;
    int t = threadIdx.x;
    int w = t >> 6;
    int lane = t & 63;
    int half = lane >> 5;
    int u = lane & 31;
    int node = blk * 8 + w * 2 + half;
    bool nv = (node < N);
    int nodec = nv ? node : (N - 1);
    int beg = rowptr[nodec];
    int deg = nv ? cnt[nodec] : 0;
    int degO = __shfl_xor(deg, 32);
    int degmax = (deg > degO) ? deg : degO;
    if (degmax <= 0) return;   // uniform across wave

    int hh = u >> 3;                           // phase-local head 0..3
    float4 ad4 = *(const float4*)&a_dst[(size_t)nodec * 8 + p * 4];

    float* myev = &evs[w][half][0];
    int*   mycl = &cls[w][half][0];

    float den = 0.f, n0 = 0.f, n1 = 0.f;
    int c = 0;
    while (c < degmax) {
        int slot = c + u;
        int slotc = (slot < deg) ? slot : (deg - 1);
        if (slotc < 0) slotc = 0;
        int su = (int)col[beg + slotc];
        float4 as4 = *(const float4*)&a_src[(size_t)su * 8 + p * 4];
        bool valid = (slot < deg);
        float e0 = valid ? __expf(lrelu(as4.x + ad4.x)) : 0.f;
        float e1 = valid ? __expf(lrelu(as4.y + ad4.y)) : 0.f;
        float e2 = valid ? __expf(lrelu(as4.z + ad4.z)) : 0.f;
        float e3 = valid ? __expf(lrelu(as4.w + ad4.w)) : 0.f;
        *(float4*)&myev[u * 4] = make_float4(e0, e1, e2, e3);
        mycl[u] = su;
        // wave-synchronous LDS: single-wave producer/consumer, no barrier

        int ccm = degmax - c; ccm = (ccm < 32) ? ccm : 32;
        int last = ccm - 1;
        // depth-3 pipeline prologue (clamped)
        int s0 = mycl[0];
        unsigned int u0 = hp[s0 * 32 + u];
        int i1 = (1 < last) ? 1 : last;
        int s1 = mycl[i1];
        unsigned int u1 = hp[s1 * 32 + u];
        int i2 = (2 < last) ? 2 : last;
        int s2 = mycl[i2];
        unsigned int u2 = hp[s2 * 32 + u];
        int body = ccm - 3;
        int i = 0;
#pragma unroll 4
        for (; i < body; ++i) {
            int sN = mycl[i + 3];                // unclamped: i+3 <= last
            unsigned int uN = hp[sN * 32 + u];
            float ev = myev[i * 4 + hh];
            den += ev;
            n0 = fmaf(ev, bf_lo(u0), n0);
            n1 = fmaf(ev, bf_hi(u0), n1);
            u0 = u1; u1 = u2; u2 = uN;
        }
        for (; i < ccm; ++i) {                   // drain: no loads
            float ev = myev[i * 4 + hh];
            den += ev;
            n0 = fmaf(ev, bf_lo(u0), n0);
            n1 = fmaf(ev, bf_hi(u0), n1);
            u0 = u1; u1 = u2;
        }
        c += 32;
    }
    if (nv) {
        float inv = 1.f / (den + 1e-16f);
        int ch = p * 64 + 2 * u;
        float2 b = *(const float2*)&bias1[ch];
        float o0 = fmaf(n0, inv, b.x), o1 = fmaf(n1, inv, b.y);
        unsigned short h0 = f2bfu(o0), h1 = f2bfu(o1);
        float l0 = o0 - bfu2f(h0), l1 = o1 - bfu2f(h1);
        size_t idx = (size_t)node * 64 + p * 32 + u;
        out1h[idx] = (unsigned int)h0 | ((unsigned int)h1 << 16);
        out1l[idx] = (unsigned int)f2bfu(l0) | ((unsigned int)f2bfu(l1) << 16);
    }
}

// ---------------------------------------------------------------------------
// GEMM2 via MFMA: h2 = out1 @ W2 ([N,128]@[128,40->48]); out1 consumed as
// hi/lo bf16; 24 mfma. Emits bf16 h2 rows padded to 64 ushorts (one
// cacheline per row) + fused fp32 a_src2/a_dst2.
// ---------------------------------------------------------------------------
__global__ __launch_bounds__(256) void k_gemm2(const unsigned int* __restrict__ out1h,
                                               const unsigned int* __restrict__ out1l,
                                               const bf16x8* __restrict__ W2p,
                                               const float* __restrict__ att_s2,
                                               const float* __restrict__ att_d2,
                                               unsigned short* __restrict__ h2s,
                                               float* __restrict__ a_src2,
                                               float* __restrict__ a_dst2, int N) {
    int t = threadIdx.x;
    int w = t >> 6, lane = t & 63, quad = lane >> 4, n16 = lane & 15;
    int row0 = blockIdx.x * 64 + w * 16;
    int arow = row0 + n16; if (arow >= N) arow = N - 1;

    bf16x8 ah[4], al[4];
#pragma unroll
    for (int c = 0; c < 4; ++c) {
        size_t base = (size_t)arow * 64 + (c * 32 + quad * 8) / 2;
        union { uint4 u; bf16x8 b; } hu, lu;
        hu.u = *(const uint4*)&out1h[base];
        lu.u = *(const uint4*)&out1l[base];
        ah[c] = hu.b;
        al[c] = lu.b;
    }

    f32x4 acc[3];
#pragma unroll
    for (int ct = 0; ct < 3; ++ct) acc[ct] = (f32x4){0.f, 0.f, 0.f, 0.f};

    const uint4* wp4 = (const uint4*)W2p;
#pragma unroll
    for (int ct = 0; ct < 3; ++ct) {
#pragma unroll
        for (int c = 0; c < 4; ++c) {
            union { uint4 u; bf16x8 b; } bu;
            bu.u = wp4[((ct * 4 + c) * 4 + quad) * 16 + n16];
            acc[ct] = __builtin_amdgcn_mfma_f32_16x16x32_bf16(ah[c], bu.b, acc[ct], 0, 0, 0);
            acc[ct] = __builtin_amdgcn_mfma_f32_16x16x32_bf16(al[c], bu.b, acc[ct], 0, 0, 0);
        }
    }

    float asv[3], adv[3];
#pragma unroll
    for (int ct = 0; ct < 3; ++ct) {
        int ch = ct * 16 + n16;
        asv[ct] = (ch < 40) ? att_s2[ch] : 0.f;
        adv[ct] = (ch < 40) ? att_d2[ch] : 0.f;
    }
    int nodeb = row0 + quad * 4;
#pragma unroll
    for (int reg = 0; reg < 4; ++reg) {
        int node = nodeb + reg;
        float ps = 0.f, pd = 0.f;
#pragma unroll
        for (int ct = 0; ct < 3; ++ct) {
            float hv = acc[ct][reg];
            ps = fmaf(hv, asv[ct], ps);
            pd = fmaf(hv, adv[ct], pd);
            int ch = ct * 16 + n16;
            if (node < N && ch < 40) h2s[(size_t)node * 64 + ch] = f2bfu(hv);
        }
#pragma unroll
        for (int m = 1; m < 16; m <<= 1) {
            ps += __shfl_xor(ps, m);
            pd += __shfl_xor(pd, m);
        }
        if (node < N && n16 == 0) {
            a_src2[node] = ps;
            a_dst2[node] = pd;
        }
    }
}

// ---------------------------------------------------------------------------
// Layer-2 aggregation (H=1, C=40). Two nodes per wave (32 lanes each); lane
// u<20 owns channels 2u,2u+1; h2 rows = one cacheline. Depth-3 prefetch with
// unclamped unrolled body + load-free drain tail. Writes final output.
// ---------------------------------------------------------------------------
__global__ __launch_bounds__(256) void k_aggr2(const int* __restrict__ rowptr,
                                               const int* __restrict__ cnt,
                                               const unsigned short* __restrict__ col,
                                               const float* __restrict__ a_src,
                                               const float* __restrict__ a_dst,
                                               const unsigned int* __restrict__ h2b,
                                               const float* __restrict__ bias2,
                                               float* __restrict__ out, int N) {
    __shared__ float evs[4][2][32];
    __shared__ int   cls[4][2][32];
    int t = threadIdx.x;
    int w = t >> 6;
    int lane = t & 63;
    int half = lane >> 5;
    int u = lane & 31;
    int node = blockIdx.x * 8 + w * 2 + half;
    bool nv = (node < N);
    int nodec = nv ? node : (N - 1);
    int beg = rowptr[nodec];
    int deg = nv ? cnt[nodec] : 0;
    int degO = __shfl_xor(deg, 32);
    int degmax = (deg > degO) ? deg : degO;
    if (degmax <= 0) return;

    int ucl = (u < 20) ? u : 19;
    float ad = a_dst[nodec];
    float* myev = &evs[w][half][0];
    int*   mycl = &cls[w][half][0];

    float den = 0.f, a0 = 0.f, a1 = 0.f;
    int c = 0;
    while (c < degmax) {
        int slot = c + u;
        int slotc = (slot < deg) ? slot : (deg - 1);
        if (slotc < 0) slotc = 0;
        int su = (int)col[beg + slotc];
        float ev = (slot < deg) ? __expf(lrelu(a_src[su] + ad)) : 0.f;
        myev[u] = ev;
        mycl[u] = su;

        int ccm = degmax - c; ccm = (ccm < 32) ? ccm : 32;
        int last = ccm - 1;
        int s0 = mycl[0];
        unsigned int u0 = h2b[s0 * 32 + ucl];
        int i1 = (1 < last) ? 1 : last;
        int s1 = mycl[i1];
        unsigned int u1 = h2b[s1 * 32 + ucl];
        int i2 = (2 < last) ? 2 : last;
        int s2 = mycl[i2];
        unsigned int u2 = h2b[s2 * 32 + ucl];
        int body = ccm - 3;
        int i = 0;
#pragma unroll 4
        for (; i < body; ++i) {
            int sN = mycl[i + 3];
            unsigned int uN = h2b[sN * 32 + ucl];
            float evv = myev[i];
            den += evv;
            a0 = fmaf(evv, bf_lo(u0), a0);
            a1 = fmaf(evv, bf_hi(u0), a1);
            u0 = u1; u1 = u2; u2 = uN;
        }
        for (; i < ccm; ++i) {
            float evv = myev[i];
            den += evv;
            a0 = fmaf(evv, bf_lo(u0), a0);
            a1 = fmaf(evv, bf_hi(u0), a1);
            u0 = u1; u1 = u2;
        }
        c += 32;
    }
    if (nv && u < 20) {
        float inv = 1.f / (den + 1e-16f);
        float2 b = *(const float2*)&bias2[2 * u];
        float2 o = make_float2(fmaf(a0, inv, b.x), fmaf(a1, inv, b.y));
        *(float2*)&out[(size_t)node * 40 + 2 * u] = o;
    }
}

// ---------------------------------------------------------------------------
extern "C" void kernel_launch(void* const* d_in, const int* in_sizes, int n_in,
                              void* d_out, int out_size, void* d_ws, size_t ws_size,
                              hipStream_t stream) {
    const float* x   = (const float*)d_in[0];
    const int*   ei  = (const int*)d_in[1];
    const float* W1  = (const float*)d_in[2];
    const float* as1 = (const float*)d_in[3];
    const float* ad1 = (const float*)d_in[4];
    const float* b1  = (const float*)d_in[5];
    const float* W2  = (const float*)d_in[6];
    const float* as2 = (const float*)d_in[7];
    const float* ad2 = (const float*)d_in[8];
    const float* b2  = (const float*)d_in[9];

    int N = in_sizes[0] / 128;
    int E = in_sizes[1] / 2;
    int EN = E + N;
    size_t Np = (size_t)((N + 3) & ~3);
    size_t ENp = ((size_t)EN + 3) & ~3;

    float* ws = (float*)d_ws;
    unsigned int* out1h = (unsigned int*)ws; ws += Np * 64;  // hi bf16 pairs
    unsigned int* out1l = (unsigned int*)ws; ws += Np * 64;  // lo bf16 pairs
    unsigned int* h1A = (unsigned int*)ws; ws += Np * 32;    // ch 0-63, bf16x2
    unsigned int* h1Bp = (unsigned int*)ws; ws += Np * 32;   // ch 64-127
    unsigned int* h2b = (unsigned int*)ws; ws += Np * 32;    // padded 128 B rows
    float* a_src1  = ws; ws += Np * 8;
    float* a_dst1  = ws; ws += Np * 8;
    float* a_src2v = ws; ws += Np;
    float* a_dst2v = ws; ws += Np;
    bf16x8* Wp  = (bf16x8*)ws; ws += 2048 * 4;               // 32 KB repacked W1
    bf16x8* W2p = (bf16x8*)ws; ws += 768 * 4;                // 12 KB repacked W2
    int* cnt    = (int*)ws; ws += Np;
    int* rowptr = (int*)ws; ws += Np;
    int* psum   = (int*)ws; ws += 256;
    unsigned short* col  = (unsigned short*)ws; ws += ENp / 2 + 4;
    unsigned short* rank = (unsigned short*)ws; ws += ENp / 2 + 4;

    int nb = (N + 1023) / 1024;  // scan blocks (<=256)
    int npre = (N > 2816 ? N : 2816);

    k_prep<<<(npre + 255) / 256, 256, 0, stream>>>(W1, Wp, W2, W2p, cnt, N);
    k_hist<<<(EN + 255) / 256, 256, 0, stream>>>(ei, E, N, cnt, rank);
    k_scan_part<<<nb, 256, 0, stream>>>(cnt, N, psum);
    k_scan_add<<<nb, 256, 0, stream>>>(cnt, N, psum, rowptr);
    k_scatter<<<(EN + 255) / 256, 256, 0, stream>>>(ei, E, N, rowptr, rank, col);

    k_gemm1<<<(N + 63) / 64, 256, 0, stream>>>(x, Wp, as1, ad1,
                                               (unsigned short*)h1A, (unsigned short*)h1Bp,
                                               a_src1, a_dst1, N);
    int nag = (N + 7) / 8;
    k_aggr1<<<2 * nag, 256, 0, stream>>>(rowptr, cnt, col, a_src1, a_dst1,
                                         h1A, h1Bp, b1, out1h, out1l, N, nag);
    k_gemm2<<<(N + 63) / 64, 256, 0, stream>>>(out1h, out1l, W2p, as2, ad2,
                                               (unsigned short*)h2b, a_src2v, a_dst2v, N);
    k_aggr2<<<nag, 256, 0, stream>>>(rowptr, cnt, col, a_src2v, a_dst2v, h2b, b2, (float*)d_out, N);
}